// Round 9
// baseline (150.757 us; speedup 1.0000x reference)
//
#include <hip/hip_runtime.h>
#include <hip/hip_bf16.h>
#include <stdint.h>

typedef __bf16 bf16;
typedef __bf16 bf16x4 __attribute__((ext_vector_type(4)));
typedef __bf16 bf16x8 __attribute__((ext_vector_type(8)));
typedef float  f32x4  __attribute__((ext_vector_type(4)));
typedef float  f32x16 __attribute__((ext_vector_type(16)));

#define MFMA32(A_, B_, C_) __builtin_amdgcn_mfma_f32_32x32x16_bf16((A_), (B_), (C_), 0, 0, 0)

#define QSCALE 0.1803368801111137f  // 0.125 * log2(e), folded into Wq/bq

__device__ __forceinline__ void gload_lds16(const void* g, void* l) {
  __builtin_amdgcn_global_load_lds(
      (const __attribute__((address_space(1))) unsigned int*)g,
      (__attribute__((address_space(3))) unsigned int*)l, 16, 0, 0);
}

__device__ __forceinline__ unsigned pk2(float lo, float hi_) {
  union { bf16 h[2]; unsigned u; } t;
  t.h[0] = (bf16)lo; t.h[1] = (bf16)hi_;
  return t.u;
}

__device__ __forceinline__ float fast_exp2(float x) {
#if __has_builtin(__builtin_amdgcn_exp2f)
  return __builtin_amdgcn_exp2f(x);
#else
  return exp2f(x);
#endif
}

// ---------------------------------------------------------------------------
// prep_ln: blocks 0..773 = weight transposes + bias pack; 774..1797 = LN1.
// ---------------------------------------------------------------------------
__global__ __launch_bounds__(256) void prep_ln(const float* __restrict__ Wq,
                                               const float* __restrict__ Wk,
                                               const float* __restrict__ Wv,
                                               const float* __restrict__ Wo,
                                               const float* __restrict__ W1,
                                               const float* __restrict__ W2,
                                               const float* __restrict__ bq,
                                               const float* __restrict__ bk,
                                               const float* __restrict__ bv,
                                               bf16* __restrict__ wqkvT, bf16* __restrict__ woT,
                                               bf16* __restrict__ w1T, bf16* __restrict__ w2T,
                                               float* __restrict__ bqkv,
                                               const float* __restrict__ x,
                                               const float* __restrict__ ln1s,
                                               const float* __restrict__ ln1b,
                                               bf16* __restrict__ h) {
  const int b = blockIdx.x;
  if (b >= 774) {  // ---- LayerNorm rows ----
    const int w = threadIdx.x >> 6, l = threadIdx.x & 63;
    const int row = (b - 774) * 4 + w;
    const float4* xp = (const float4*)(x + (size_t)row * 512 + l * 8);
    float4 v0 = xp[0], v1 = xp[1];
    float xv[8] = {v0.x, v0.y, v0.z, v0.w, v1.x, v1.y, v1.z, v1.w};
    float s = 0.f, q = 0.f;
#pragma unroll
    for (int j = 0; j < 8; ++j) { s += xv[j]; q += xv[j] * xv[j]; }
#pragma unroll
    for (int m = 1; m < 64; m <<= 1) { s += __shfl_xor(s, m); q += __shfl_xor(q, m); }
    const float mean = s * (1.f / 512.f);
    const float var = q * (1.f / 512.f) - mean * mean;
    const float rstd = rsqrtf(var + 1e-6f);
    const float4* scp = (const float4*)(ln1s + l * 8);
    const float4* bip = (const float4*)(ln1b + l * 8);
    float4 s0 = scp[0], s1 = scp[1], b0 = bip[0], b1 = bip[1];
    float sv[8] = {s0.x, s0.y, s0.z, s0.w, s1.x, s1.y, s1.z, s1.w};
    float bvv[8] = {b0.x, b0.y, b0.z, b0.w, b1.x, b1.y, b1.z, b1.w};
    bf16x8 ov;
#pragma unroll
    for (int j = 0; j < 8; ++j) ov[j] = (bf16)((xv[j] - mean) * rstd * sv[j] + bvv[j]);
    *(bf16x8*)(h + (size_t)row * 512 + l * 8) = ov;
    return;
  }
  if (b >= 768) {  // ---- bias pack ----
    int i = (b - 768) * 256 + threadIdx.x;
    if (i < 1536)
      bqkv[i] = (i < 512) ? bq[i] * QSCALE : (i < 1024 ? bk[i - 512] : bv[i - 1024]);
    return;
  }
  const float* in; bf16* outp; int K, N, t; float sc = 1.f;
  if (b < 64)       { in = Wq; outp = wqkvT;              K = 512;  N = 512;  t = b;       sc = QSCALE; }
  else if (b < 128) { in = Wk; outp = wqkvT + 512 * 512;  K = 512;  N = 512;  t = b - 64;  }
  else if (b < 192) { in = Wv; outp = wqkvT + 1024 * 512; K = 512;  N = 512;  t = b - 128; }
  else if (b < 256) { in = Wo; outp = woT;                K = 512;  N = 512;  t = b - 192; }
  else if (b < 512) { in = W1; outp = w1T;                K = 512;  N = 2048; t = b - 256; }
  else              { in = W2; outp = w2T;                K = 2048; N = 512;  t = b - 512; }
  const int tx = K >> 6;
  const int k0 = (t % tx) * 64, n0 = (t / tx) * 64;
  __shared__ bf16 tile[64][72];
  const int tid = threadIdx.x;
#pragma unroll
  for (int s = 0; s < 16; ++s) {
    int j = tid + s * 256;
    int r = j >> 6, c = j & 63;
    tile[r][c] = (bf16)(in[(size_t)(k0 + r) * N + n0 + c] * sc);
  }
  __syncthreads();
#pragma unroll
  for (int s = 0; s < 16; ++s) {
    int j = tid + s * 256;
    int n = j >> 6, k = j & 63;
    outp[(size_t)(n0 + n) * K + k0 + k] = tile[k][n];
  }
}

// ---------------------------------------------------------------------------
// ln2_comb: x2 = p0+p1+bo+x (fp32), h2 = LN(x2) (bf16). Partials bf16.
// ---------------------------------------------------------------------------
__global__ __launch_bounds__(256) void ln2_comb(const bf16* __restrict__ p0,
                                                const bf16* __restrict__ p1,
                                                const float* __restrict__ x,
                                                const float* __restrict__ bo,
                                                const float* __restrict__ sc,
                                                const float* __restrict__ bi,
                                                float* __restrict__ x2,
                                                bf16* __restrict__ h2) {
  const int w = threadIdx.x >> 6, l = threadIdx.x & 63;
  const int row = blockIdx.x * 4 + w;
  const size_t base = (size_t)row * 512 + l * 8;
  bf16x8 a = *(const bf16x8*)(p0 + base);
  bf16x8 b = *(const bf16x8*)(p1 + base);
  float xv[8];
#pragma unroll
  for (int j = 0; j < 2; ++j) {
    float4 c = *(const float4*)(x + base + j * 4);
    float4 d = *(const float4*)(bo + l * 8 + j * 4);
    xv[j * 4 + 0] = (float)a[j * 4 + 0] + (float)b[j * 4 + 0] + c.x + d.x;
    xv[j * 4 + 1] = (float)a[j * 4 + 1] + (float)b[j * 4 + 1] + c.y + d.y;
    xv[j * 4 + 2] = (float)a[j * 4 + 2] + (float)b[j * 4 + 2] + c.z + d.z;
    xv[j * 4 + 3] = (float)a[j * 4 + 3] + (float)b[j * 4 + 3] + c.w + d.w;
  }
  *(float4*)(x2 + base) = make_float4(xv[0], xv[1], xv[2], xv[3]);
  *(float4*)(x2 + base + 4) = make_float4(xv[4], xv[5], xv[6], xv[7]);
  float s = 0.f, q = 0.f;
#pragma unroll
  for (int j = 0; j < 8; ++j) { s += xv[j]; q += xv[j] * xv[j]; }
#pragma unroll
  for (int m = 1; m < 64; m <<= 1) { s += __shfl_xor(s, m); q += __shfl_xor(q, m); }
  const float mean = s * (1.f / 512.f);
  const float var = q * (1.f / 512.f) - mean * mean;
  const float rstd = rsqrtf(var + 1e-6f);
  const float4* scp = (const float4*)(sc + l * 8);
  const float4* bip = (const float4*)(bi + l * 8);
  float4 s0 = scp[0], s1 = scp[1], b0 = bip[0], b1 = bip[1];
  float sv[8] = {s0.x, s0.y, s0.z, s0.w, s1.x, s1.y, s1.z, s1.w};
  float bvv[8] = {b0.x, b0.y, b0.z, b0.w, b1.x, b1.y, b1.z, b1.w};
  bf16x8 ov;
#pragma unroll
  for (int j = 0; j < 8; ++j) ov[j] = (bf16)((xv[j] - mean) * rstd * sv[j] + bvv[j]);
  *(bf16x8*)(h2 + base) = ov;
}

// out = sum(parts bf16) + b2 + x2   (fp32 out); 8 elems/thread
__global__ __launch_bounds__(256) void final_comb(const bf16* __restrict__ parts, int nsplit,
                                                  const float* __restrict__ b2,
                                                  const float* __restrict__ x2,
                                                  float* __restrict__ outp) {
  const int i8 = blockIdx.x * 256 + threadIdx.x;   // 262144 total
  const size_t off = (size_t)i8 * 8;
  float acc[8];
  float4 xa = *(const float4*)(x2 + off);
  float4 xb = *(const float4*)(x2 + off + 4);
  float4 ba = *(const float4*)(b2 + (off & 511));
  float4 bb = *(const float4*)(b2 + ((off & 511) + 4));
  acc[0] = xa.x + ba.x; acc[1] = xa.y + ba.y; acc[2] = xa.z + ba.z; acc[3] = xa.w + ba.w;
  acc[4] = xb.x + bb.x; acc[5] = xb.y + bb.y; acc[6] = xb.z + bb.z; acc[7] = xb.w + bb.w;
  for (int z = 0; z < nsplit; ++z) {
    bf16x8 p = *(const bf16x8*)(parts + (size_t)z * 2097152 + off);
#pragma unroll
    for (int j = 0; j < 8; ++j) acc[j] += (float)p[j];
  }
  *(float4*)(outp + off) = make_float4(acc[0], acc[1], acc[2], acc[3]);
  *(float4*)(outp + off + 4) = make_float4(acc[4], acc[5], acc[6], acc[7]);
}

// ---------------------------------------------------------------------------
// GEMM32: 64x64 tile, 4 waves (2x2), one 32x32x16 MFMA acc per wave, BK=64,
// double-buffered, XOR-swizzled LDS (attention's verified read pattern).
// C[row=lane][col=crow(r,hi)]; crow = (r>>2)*8 + hi*4 + (r&3).
// EPI 1: +bias+res->f32   EPI 2: +bias,gelu->bf16   EPI 3: qkv split q2/k2/vd
// ---------------------------------------------------------------------------
template <int EPI>
__global__ __launch_bounds__(256, 4) void gemm32(const bf16* __restrict__ A,
                                                 const bf16* __restrict__ Bt,
                                                 const float* __restrict__ bias,
                                                 const float* __restrict__ res,
                                                 void* __restrict__ outp,
                                                 bf16* __restrict__ k2,
                                                 bf16* __restrict__ vd,
                                                 int M, int N, int K) {
  __shared__ bf16 a_lds[2][64 * 64];
  __shared__ bf16 b_lds[2][64 * 64];
  const int m0 = blockIdx.x * 64, n0 = blockIdx.y * 64;
  const int tid = threadIdx.x, l = tid & 63, w = tid >> 6;
  const int wm = w >> 1, wn = w & 1;
  const int hi = l >> 5, l5 = l & 31;
  const int lr = l >> 3;
  const int cs = (l & 7) ^ (lr & 7);
  const int swl = l5 & 7;

  const bf16* ag = A + (size_t)(m0 + w * 16 + lr) * K + cs * 8;
  const bf16* bg = Bt + (size_t)(n0 + w * 16 + lr) * K + cs * 8;
  const size_t r8 = (size_t)8 * K;

#define GS32(B_)                                                   \
  do {                                                             \
    gload_lds16(ag,      (char*)a_lds[B_] + (w * 16) * 128);       \
    gload_lds16(ag + r8, (char*)a_lds[B_] + (w * 16 + 8) * 128);   \
    gload_lds16(bg,      (char*)b_lds[B_] + (w * 16) * 128);       \
    gload_lds16(bg + r8, (char*)b_lds[B_] + (w * 16 + 8) * 128);   \
    ag += 64; bg += 64;                                            \
  } while (0)

  f32x16 acc = {};
  const int kiters = K >> 6;
  GS32(0);
  __syncthreads();
  for (int kt = 0; kt < kiters; ++kt) {
    const int cur = kt & 1;
    if (kt + 1 < kiters) GS32(cur ^ 1);
    const bf16* ab = a_lds[cur] + (wm * 32 + l5) * 64;
    const bf16* bb = b_lds[cur] + (wn * 32 + l5) * 64;
#pragma unroll
    for (int kk = 0; kk < 4; ++kk) {
      bf16x8 af = *(const bf16x8*)(ab + ((kk * 2 + hi) ^ swl) * 8);
      bf16x8 bf_ = *(const bf16x8*)(bb + ((kk * 2 + hi) ^ swl) * 8);
      acc = MFMA32(bf_, af, acc);  // A-op = Bt rows, B-op = A rows
    }
    __syncthreads();
  }
#undef GS32

  const int row = m0 + wm * 32 + l5;
#pragma unroll
  for (int rg = 0; rg < 4; ++rg) {
    const int cb = n0 + wn * 32 + rg * 8 + hi * 4;
    float4 bb4 = *(const float4*)(bias + cb);
    float v[4];
    v[0] = acc[rg * 4 + 0] + bb4.x;
    v[1] = acc[rg * 4 + 1] + bb4.y;
    v[2] = acc[rg * 4 + 2] + bb4.z;
    v[3] = acc[rg * 4 + 3] + bb4.w;
    if constexpr (EPI == 1) {
      float4 rr = *(const float4*)(res + (size_t)row * N + cb);
      *(float4*)((float*)outp + (size_t)row * N + cb) =
          make_float4(v[0] + rr.x, v[1] + rr.y, v[2] + rr.z, v[3] + rr.w);
    } else if constexpr (EPI == 2) {
      bf16x4 o;
#pragma unroll
      for (int e = 0; e < 4; ++e) {
        float t = -2.3022077697f * (v[e] + 0.044715f * v[e] * v[e] * v[e]);
        o[e] = (bf16)(v[e] / (1.f + fast_exp2(t)));
      }
      *(bf16x4*)((bf16*)outp + (size_t)row * N + cb) = o;
    } else {  // EPI 3
      bf16x4 o;
#pragma unroll
      for (int e = 0; e < 4; ++e) o[e] = (bf16)v[e];
      if (n0 < 512) {
        *(bf16x4*)((bf16*)outp + (size_t)row * 512 + cb) = o;
      } else if (n0 < 1024) {
        const int hd = (n0 - 512) >> 6, d = cb & 63;
        *(bf16x4*)(k2 + (size_t)hd * 262144 + (size_t)row * 64 + d) = o;
      } else {
        const int hd = (n0 - 1024) >> 6, d = cb & 63;
        *(bf16x4*)(vd + (size_t)hd * 262144 + (size_t)row * 64 + d) = o;
      }
    }
  }
}

// ---------------------------------------------------------------------------
// Split-K GEMM32 partial: parts[kz][M][N] bf16 raw
// ---------------------------------------------------------------------------
__global__ __launch_bounds__(256, 4) void gemm32_skp(const bf16* __restrict__ A,
                                                     const bf16* __restrict__ Bt,
                                                     bf16* __restrict__ parts,
                                                     int M, int N, int Kstride, int Kc) {
  __shared__ bf16 a_lds[2][64 * 64];
  __shared__ bf16 b_lds[2][64 * 64];
  const int m0 = blockIdx.x * 64, n0 = blockIdx.y * 64, kz = blockIdx.z;
  A += (size_t)kz * Kc;
  Bt += (size_t)kz * Kc;
  bf16* outp = parts + (size_t)kz * M * N;
  const int tid = threadIdx.x, l = tid & 63, w = tid >> 6;
  const int wm = w >> 1, wn = w & 1;
  const int hi = l >> 5, l5 = l & 31;
  const int lr = l >> 3;
  const int cs = (l & 7) ^ (lr & 7);
  const int swl = l5 & 7;

  const bf16* ag = A + (size_t)(m0 + w * 16 + lr) * Kstride + cs * 8;
  const bf16* bg = Bt + (size_t)(n0 + w * 16 + lr) * Kstride + cs * 8;
  const size_t r8 = (size_t)8 * Kstride;

#define GS32(B_)                                                   \
  do {                                                             \
    gload_lds16(ag,      (char*)a_lds[B_] + (w * 16) * 128);       \
    gload_lds16(ag + r8, (char*)a_lds[B_] + (w * 16 + 8) * 128);   \
    gload_lds16(bg,      (char*)b_lds[B_] + (w * 16) * 128);       \
    gload_lds16(bg + r8, (char*)b_lds[B_] + (w * 16 + 8) * 128);   \
    ag += 64; bg += 64;                                            \
  } while (0)

  f32x16 acc = {};
  const int kiters = Kc >> 6;
  GS32(0);
  __syncthreads();
  for (int kt = 0; kt < kiters; ++kt) {
    const int cur = kt & 1;
    if (kt + 1 < kiters) GS32(cur ^ 1);
    const bf16* ab = a_lds[cur] + (wm * 32 + l5) * 64;
    const bf16* bb = b_lds[cur] + (wn * 32 + l5) * 64;
#pragma unroll
    for (int kk = 0; kk < 4; ++kk) {
      bf16x8 af = *(const bf16x8*)(ab + ((kk * 2 + hi) ^ swl) * 8);
      bf16x8 bf_ = *(const bf16x8*)(bb + ((kk * 2 + hi) ^ swl) * 8);
      acc = MFMA32(bf_, af, acc);
    }
    __syncthreads();
  }
#undef GS32

  const int row = m0 + wm * 32 + l5;
#pragma unroll
  for (int rg = 0; rg < 4; ++rg) {
    const int cb = n0 + wn * 32 + rg * 8 + hi * 4;
    bf16x4 o;
#pragma unroll
    for (int e = 0; e < 4; ++e) o[e] = (bf16)acc[rg * 4 + e];
    *(bf16x4*)(outp + (size_t)row * N + cb) = o;
  }
}

// ---------------------------------------------------------------------------
// vtrans: vd[h][t][64] -> v2[h][p][d][32] panels (p = t/32)
// ---------------------------------------------------------------------------
__global__ __launch_bounds__(256) void vtrans(const bf16* __restrict__ vd,
                                              bf16* __restrict__ v2) {
  __shared__ bf16 tile[64][72];
  const int t0 = blockIdx.x * 64;
  const int head = blockIdx.y;
  const int tid = threadIdx.x;
#pragma unroll
  for (int s = 0; s < 16; ++s) {
    int j = tid + s * 256;
    int t = j >> 6, d = j & 63;
    tile[t][d] = vd[(size_t)head * 262144 + (size_t)(t0 + t) * 64 + d];
  }
  __syncthreads();
#pragma unroll
  for (int s = 0; s < 16; ++s) {
    int j = tid + s * 256;
    int d = j >> 6, t = j & 63;
    v2[(size_t)head * 262144 + (size_t)((t0 >> 5) + (t >> 5)) * 2048 + d * 32 + (t & 31)] =
        tile[t][d];
  }
}

// ---------------------------------------------------------------------------
// Flash attention v7 (unchanged from R8): block-shared LDS staging, dbuf,
// one barrier/tile; constant-max in-register softmax; raw v_exp2; permlane
// pack. Q from dense q2. Raw O/l partials; attn_comb divides (exact).
// ---------------------------------------------------------------------------
__global__ __launch_bounds__(256, 4) void attn_k(const bf16* __restrict__ q2,
                                                 const bf16* __restrict__ k2,
                                                 const bf16* __restrict__ v2,
                                                 bf16* __restrict__ opart,
                                                 float* __restrict__ lpart) {
  const int bid = blockIdx.x;
  const int head = bid & 7;          // one head per XCD (L2 locality)
  const int qt = (bid >> 3) & 63;
  const int ks = bid >> 9;
  const int w = threadIdx.x >> 6, l = threadIdx.x & 63;
  const int hi = l >> 5, l5 = l & 31;
  const int pair = w >> 1, wq = w & 1;

  __shared__ __align__(16) char smem[32768];
  char* kt_l = smem + pair * 16384;   // [2][4096] B
  char* vt_l = kt_l + 8192;           // [2][4096] B

  const int qrow0 = qt * 64 + wq * 32;
  const bf16* qb = q2 + (size_t)(qrow0 + l5) * 512 + head * 64;
  bf16x8 qf[4];
#pragma unroll
  for (int cc = 0; cc < 4; ++cc) qf[cc] = *(const bf16x8*)(qb + cc * 16 + hi * 8);

  const int kstart = ks * 2048 + pair * 1024;

  const int lr = l >> 3;
  const int lc3 = (l & 7) ^ lr;
  const char* kg = (const char*)k2 + (size_t)head * 524288 + (size_t)kstart * 128 +
                   (wq * 16 + lr) * 128 + lc3 * 16;
  const char* vg = (const char*)v2 + (size_t)head * 524288 + (size_t)(kstart >> 5) * 4096 +
                   (lc3 >> 2) * 2048 + (wq * 16 + lr) * 64 + (lc3 & 3) * 16;
  const int kdst = wq * 2048;

#define STAGE(B_)                                                            \
  do {                                                                       \
    gload_lds16(kg,        kt_l + (B_) * 4096 + kdst);                       \
    gload_lds16(kg + 1024, kt_l + (B_) * 4096 + kdst + 1024);                \
    gload_lds16(vg,        vt_l + (B_) * 4096 + kdst);                       \
    gload_lds16(vg + 512,  vt_l + (B_) * 4096 + kdst + 1024);                \
    kg += 4096; vg += 4096;                                                  \
  } while (0)

  STAGE(0);
  __syncthreads();

  f32x16 o0 = {}, o1 = {};
  float psum = 0.f;
  const int swl = l5 & 7;
  const char* kbase = kt_l + l5 * 128;
  const char* vbase = vt_l + l5 * 128;

  for (int t = 0; t < 32; ++t) {
    const int cur = t & 1;
    if (t < 31) STAGE(cur ^ 1);

    __builtin_amdgcn_s_setprio(1);
    f32x16 s = {};
#pragma unroll
    for (int cc = 0; cc < 4; ++cc) {
      bf16x8 kf = *(const bf16x8*)(kbase + cur * 4096 + ((cc * 2 + hi) ^ swl) * 16);
      s = MFMA32(kf, qf[cc], s);
    }
    __builtin_amdgcn_s_setprio(0);

#pragma unroll
    for (int c = 0; c < 2; ++c) {
      float p[8];
#pragma unroll
      for (int j = 0; j < 8; ++j) p[j] = fast_exp2(s[c * 8 + j]);
      psum += ((p[0] + p[1]) + (p[2] + p[3])) + ((p[4] + p[5]) + (p[6] + p[7]));
      unsigned X = pk2(p[0], p[1]), X2 = pk2(p[2], p[3]);
      unsigned Y = pk2(p[4], p[5]), Y2 = pk2(p[6], p[7]);
      asm volatile("v_permlane32_swap_b32 %0, %1" : "+v"(X), "+v"(Y));
      asm volatile("v_permlane32_swap_b32 %0, %1" : "+v"(X2), "+v"(Y2));
      union { unsigned wd[4]; bf16x8 v; } pa;
      pa.wd[0] = X; pa.wd[1] = X2; pa.wd[2] = Y; pa.wd[3] = Y2;
      bf16x8 vf0 = *(const bf16x8*)(vbase + cur * 4096 + ((c * 2 + hi) ^ swl) * 16);
      bf16x8 vf1 = *(const bf16x8*)(vbase + cur * 4096 + ((4 + c * 2 + hi) ^ swl) * 16);
      __builtin_amdgcn_s_setprio(1);
      o0 = MFMA32(vf0, pa.v, o0);
      o1 = MFMA32(vf1, pa.v, o1);
      __builtin_amdgcn_s_setprio(0);
    }
    __syncthreads();
  }
#undef STAGE

  float* comb = (float*)smem;
  if (w >= 2) {
    float* cb = comb + ((w - 2) * 64 + l) * 33;
#pragma unroll
    for (int r = 0; r < 16; ++r) { cb[r] = o0[r]; cb[16 + r] = o1[r]; }
    cb[32] = psum;
  }
  __syncthreads();
  if (w < 2) {
    const float* cb = comb + (w * 64 + l) * 33;
#pragma unroll
    for (int r = 0; r < 16; ++r) { o0[r] += cb[r]; o1[r] += cb[16 + r]; }
    psum += cb[32];
    const float lsum = psum + __shfl_xor(psum, 32);
    bf16* ob = opart + (size_t)ks * 4096 * 512 + (size_t)(qrow0 + l5) * 512 + head * 64;
#pragma unroll
    for (int dt = 0; dt < 2; ++dt)
#pragma unroll
      for (int rg = 0; rg < 4; ++rg) {
        bf16x4 vv;
#pragma unroll
        for (int e = 0; e < 4; ++e) {
          const float ov = (dt == 0) ? o0[rg * 4 + e] : o1[rg * 4 + e];
          vv[e] = (bf16)ov;
        }
        *(bf16x4*)(ob + dt * 32 + rg * 8 + hi * 4) = vv;
      }
    if (hi == 0) lpart[(ks * 8 + head) * 4096 + qrow0 + l5] = lsum;
  }
}

// attnb[t][col] = (op0+op1)/(l0+l1)
__global__ __launch_bounds__(256) void attn_comb(const bf16* __restrict__ op,
                                                 const float* __restrict__ lp,
                                                 bf16* __restrict__ ob) {
  const int idx = blockIdx.x * 256 + threadIdx.x;   // 262144 = 4096 * 64
  const int t = idx >> 6, c8 = idx & 63;
  const int head = c8 >> 3;
  const size_t o = (size_t)t * 512 + c8 * 8;
  bf16x8 a = *(const bf16x8*)(op + o);
  bf16x8 b = *(const bf16x8*)(op + 2097152 + o);
  const float inv = 1.f / (lp[head * 4096 + t] + lp[32768 + head * 4096 + t]);
  bf16x8 r;
#pragma unroll
  for (int j = 0; j < 8; ++j) r[j] = (bf16)(((float)a[j] + (float)b[j]) * inv);
  *(bf16x8*)(ob + o) = r;
}

// ---------------------------------------------------------------------------
extern "C" void kernel_launch(void* const* d_in, const int* in_sizes, int n_in,
                              void* d_out, int out_size, void* d_ws, size_t ws_size,
                              hipStream_t stream) {
  const float* x    = (const float*)d_in[0];
  const float* ln1s = (const float*)d_in[1];
  const float* ln1b = (const float*)d_in[2];
  const float* Wq   = (const float*)d_in[3];
  const float* bq   = (const float*)d_in[4];
  const float* Wk   = (const float*)d_in[5];
  const float* bk   = (const float*)d_in[6];
  const float* Wv   = (const float*)d_in[7];
  const float* bv   = (const float*)d_in[8];
  const float* Wo   = (const float*)d_in[9];
  const float* bo   = (const float*)d_in[10];
  const float* ln2s = (const float*)d_in[11];
  const float* ln2b = (const float*)d_in[12];
  const float* W1   = (const float*)d_in[13];
  const float* b1   = (const float*)d_in[14];
  const float* W2   = (const float*)d_in[15];
  const float* b2   = (const float*)d_in[16];
  float* out = (float*)d_out;

  char* ws = (char*)d_ws;
  bf16*  wqkvT = (bf16*)(ws + 0);          // [1536][512] 1.5M
  bf16*  woT   = (bf16*)(ws + 1572864);    // [512][512]  0.5M
  bf16*  w1T   = (bf16*)(ws + 2097152);    // [2048][512] 2M
  bf16*  w2T   = (bf16*)(ws + 4194304);    // [512][2048] 2M
  float* bqkv  = (float*)(ws + 6291456);   // -> 6299648
  float* lpart = (float*)(ws + 6299648);   // 256K -> 6561792
  bf16*  opart = (bf16*)(ws + 6561792);    // [2][4096][512] 8M -> 14950400
  float* x2    = (float*)(ws + 6561792);   // overlays opart (disjoint lifetime)
  bf16*  h     = (bf16*)(ws + 14950400);   // 4M -> 19144704 (h / attnb / h2)
  bf16*  q2    = (bf16*)(ws + 19144704);   // 4M -> 23339008
  bf16*  k2    = (bf16*)(ws + 23339008);   // 4M -> 27533312
  bf16*  v2    = (bf16*)(ws + 27533312);   // 4M -> 31727616
  bf16*  vd    = (bf16*)(ws + 31727616);   // 4M -> 35921920
  bf16*  attnb = h;
  bf16*  h2    = h;
  bf16*  wop   = (bf16*)(ws + 19144704);   // 2x4M bf16 over dead q2/k2
  bf16*  gbuf  = (bf16*)(ws + 19144704);   // ffn1 out 16M (over dead wop/q2..vd)
  bf16*  f2p   = (bf16*)(ws + 35921920);   // gated bf16 partials
  const size_t need4 = 35921920 + 4ull * 4194304;
  const size_t need2 = 35921920 + 2ull * 4194304;

  prep_ln<<<1798, 256, 0, stream>>>(Wq, Wk, Wv, Wo, W1, W2, bq, bk, bv,
                                    wqkvT, woT, w1T, w2T, bqkv, x, ln1s, ln1b, h);
  gemm32<3><<<dim3(64, 24), 256, 0, stream>>>(h, wqkvT, bqkv, nullptr, q2, k2, vd,
                                              4096, 1536, 512);
  vtrans<<<dim3(64, 8), 256, 0, stream>>>(vd, v2);
  attn_k<<<1024, 256, 0, stream>>>(q2, k2, v2, opart, lpart);
  attn_comb<<<1024, 256, 0, stream>>>(opart, lpart, attnb);
  gemm32_skp<<<dim3(64, 8, 2), 256, 0, stream>>>(attnb, woT, wop, 4096, 512, 512, 256);
  ln2_comb<<<1024, 256, 0, stream>>>(wop, wop + 2097152, x, bo, ln2s, ln2b, x2, h2);
  gemm32<2><<<dim3(64, 32), 256, 0, stream>>>(h2, w1T, b1, nullptr, gbuf, nullptr, nullptr,
                                              4096, 2048, 512);
  if (ws_size >= need4) {
    gemm32_skp<<<dim3(64, 8, 4), 256, 0, stream>>>(gbuf, w2T, f2p, 4096, 512, 2048, 512);
    final_comb<<<1024, 256, 0, stream>>>(f2p, 4, b2, x2, out);
  } else if (ws_size >= need2) {
    gemm32_skp<<<dim3(64, 8, 2), 256, 0, stream>>>(gbuf, w2T, f2p, 4096, 512, 2048, 1024);
    final_comb<<<1024, 256, 0, stream>>>(f2p, 2, b2, x2, out);
  } else {
    gemm32<1><<<dim3(64, 8), 256, 0, stream>>>(gbuf, w2T, b2, x2, out, nullptr, nullptr,
                                               4096, 512, 2048);
  }
}

// Round 10
// 146.825 us; speedup vs baseline: 1.0268x; 1.0268x over previous
//
#include <hip/hip_runtime.h>
#include <hip/hip_bf16.h>
#include <stdint.h>

typedef __bf16 bf16;
typedef __bf16 bf16x4 __attribute__((ext_vector_type(4)));
typedef __bf16 bf16x8 __attribute__((ext_vector_type(8)));
typedef float  f32x4  __attribute__((ext_vector_type(4)));
typedef float  f32x16 __attribute__((ext_vector_type(16)));

#define MFMA32(A_, B_, C_) __builtin_amdgcn_mfma_f32_32x32x16_bf16((A_), (B_), (C_), 0, 0, 0)

#define QSCALE 0.1803368801111137f  // 0.125 * log2(e), folded into Wq/bq

__device__ __forceinline__ void gload_lds16(const void* g, void* l) {
  __builtin_amdgcn_global_load_lds(
      (const __attribute__((address_space(1))) unsigned int*)g,
      (__attribute__((address_space(3))) unsigned int*)l, 16, 0, 0);
}

__device__ __forceinline__ unsigned pk2(float lo, float hi_) {
  union { bf16 h[2]; unsigned u; } t;
  t.h[0] = (bf16)lo; t.h[1] = (bf16)hi_;
  return t.u;
}

__device__ __forceinline__ float fast_exp2(float x) {
#if __has_builtin(__builtin_amdgcn_exp2f)
  return __builtin_amdgcn_exp2f(x);
#else
  return exp2f(x);
#endif
}

// ---------------------------------------------------------------------------
// prep_ln: blocks 0..773 = weight transposes + bias pack; 774..1797 = LN1.
// ---------------------------------------------------------------------------
__global__ __launch_bounds__(256) void prep_ln(const float* __restrict__ Wq,
                                               const float* __restrict__ Wk,
                                               const float* __restrict__ Wv,
                                               const float* __restrict__ Wo,
                                               const float* __restrict__ W1,
                                               const float* __restrict__ W2,
                                               const float* __restrict__ bq,
                                               const float* __restrict__ bk,
                                               const float* __restrict__ bv,
                                               bf16* __restrict__ wqkvT, bf16* __restrict__ woT,
                                               bf16* __restrict__ w1T, bf16* __restrict__ w2T,
                                               float* __restrict__ bqkv,
                                               const float* __restrict__ x,
                                               const float* __restrict__ ln1s,
                                               const float* __restrict__ ln1b,
                                               bf16* __restrict__ h) {
  const int b = blockIdx.x;
  if (b >= 774) {  // ---- LayerNorm rows ----
    const int w = threadIdx.x >> 6, l = threadIdx.x & 63;
    const int row = (b - 774) * 4 + w;
    const float4* xp = (const float4*)(x + (size_t)row * 512 + l * 8);
    float4 v0 = xp[0], v1 = xp[1];
    float xv[8] = {v0.x, v0.y, v0.z, v0.w, v1.x, v1.y, v1.z, v1.w};
    float s = 0.f, q = 0.f;
#pragma unroll
    for (int j = 0; j < 8; ++j) { s += xv[j]; q += xv[j] * xv[j]; }
#pragma unroll
    for (int m = 1; m < 64; m <<= 1) { s += __shfl_xor(s, m); q += __shfl_xor(q, m); }
    const float mean = s * (1.f / 512.f);
    const float var = q * (1.f / 512.f) - mean * mean;
    const float rstd = rsqrtf(var + 1e-6f);
    const float4* scp = (const float4*)(ln1s + l * 8);
    const float4* bip = (const float4*)(ln1b + l * 8);
    float4 s0 = scp[0], s1 = scp[1], b0 = bip[0], b1 = bip[1];
    float sv[8] = {s0.x, s0.y, s0.z, s0.w, s1.x, s1.y, s1.z, s1.w};
    float bvv[8] = {b0.x, b0.y, b0.z, b0.w, b1.x, b1.y, b1.z, b1.w};
    bf16x8 ov;
#pragma unroll
    for (int j = 0; j < 8; ++j) ov[j] = (bf16)((xv[j] - mean) * rstd * sv[j] + bvv[j]);
    *(bf16x8*)(h + (size_t)row * 512 + l * 8) = ov;
    return;
  }
  if (b >= 768) {  // ---- bias pack ----
    int i = (b - 768) * 256 + threadIdx.x;
    if (i < 1536)
      bqkv[i] = (i < 512) ? bq[i] * QSCALE : (i < 1024 ? bk[i - 512] : bv[i - 1024]);
    return;
  }
  const float* in; bf16* outp; int K, N, t; float sc = 1.f;
  if (b < 64)       { in = Wq; outp = wqkvT;              K = 512;  N = 512;  t = b;       sc = QSCALE; }
  else if (b < 128) { in = Wk; outp = wqkvT + 512 * 512;  K = 512;  N = 512;  t = b - 64;  }
  else if (b < 192) { in = Wv; outp = wqkvT + 1024 * 512; K = 512;  N = 512;  t = b - 128; }
  else if (b < 256) { in = Wo; outp = woT;                K = 512;  N = 512;  t = b - 192; }
  else if (b < 512) { in = W1; outp = w1T;                K = 512;  N = 2048; t = b - 256; }
  else              { in = W2; outp = w2T;                K = 2048; N = 512;  t = b - 512; }
  const int tx = K >> 6;
  const int k0 = (t % tx) * 64, n0 = (t / tx) * 64;
  __shared__ bf16 tile[64][72];
  const int tid = threadIdx.x;
#pragma unroll
  for (int s = 0; s < 16; ++s) {
    int j = tid + s * 256;
    int r = j >> 6, c = j & 63;
    tile[r][c] = (bf16)(in[(size_t)(k0 + r) * N + n0 + c] * sc);
  }
  __syncthreads();
#pragma unroll
  for (int s = 0; s < 16; ++s) {
    int j = tid + s * 256;
    int n = j >> 6, k = j & 63;
    outp[(size_t)(n0 + n) * K + k0 + k] = tile[k][n];
  }
}

// ---------------------------------------------------------------------------
// ln2_comb: x2 = p0+p1+bo+x (fp32), h2 = LN(x2) (bf16). Partials bf16.
// ---------------------------------------------------------------------------
__global__ __launch_bounds__(256) void ln2_comb(const bf16* __restrict__ p0,
                                                const bf16* __restrict__ p1,
                                                const float* __restrict__ x,
                                                const float* __restrict__ bo,
                                                const float* __restrict__ sc,
                                                const float* __restrict__ bi,
                                                float* __restrict__ x2,
                                                bf16* __restrict__ h2) {
  const int w = threadIdx.x >> 6, l = threadIdx.x & 63;
  const int row = blockIdx.x * 4 + w;
  const size_t base = (size_t)row * 512 + l * 8;
  bf16x8 a = *(const bf16x8*)(p0 + base);
  bf16x8 b = *(const bf16x8*)(p1 + base);
  float xv[8];
#pragma unroll
  for (int j = 0; j < 2; ++j) {
    float4 c = *(const float4*)(x + base + j * 4);
    float4 d = *(const float4*)(bo + l * 8 + j * 4);
    xv[j * 4 + 0] = (float)a[j * 4 + 0] + (float)b[j * 4 + 0] + c.x + d.x;
    xv[j * 4 + 1] = (float)a[j * 4 + 1] + (float)b[j * 4 + 1] + c.y + d.y;
    xv[j * 4 + 2] = (float)a[j * 4 + 2] + (float)b[j * 4 + 2] + c.z + d.z;
    xv[j * 4 + 3] = (float)a[j * 4 + 3] + (float)b[j * 4 + 3] + c.w + d.w;
  }
  *(float4*)(x2 + base) = make_float4(xv[0], xv[1], xv[2], xv[3]);
  *(float4*)(x2 + base + 4) = make_float4(xv[4], xv[5], xv[6], xv[7]);
  float s = 0.f, q = 0.f;
#pragma unroll
  for (int j = 0; j < 8; ++j) { s += xv[j]; q += xv[j] * xv[j]; }
#pragma unroll
  for (int m = 1; m < 64; m <<= 1) { s += __shfl_xor(s, m); q += __shfl_xor(q, m); }
  const float mean = s * (1.f / 512.f);
  const float var = q * (1.f / 512.f) - mean * mean;
  const float rstd = rsqrtf(var + 1e-6f);
  const float4* scp = (const float4*)(sc + l * 8);
  const float4* bip = (const float4*)(bi + l * 8);
  float4 s0 = scp[0], s1 = scp[1], b0 = bip[0], b1 = bip[1];
  float sv[8] = {s0.x, s0.y, s0.z, s0.w, s1.x, s1.y, s1.z, s1.w};
  float bvv[8] = {b0.x, b0.y, b0.z, b0.w, b1.x, b1.y, b1.z, b1.w};
  bf16x8 ov;
#pragma unroll
  for (int j = 0; j < 8; ++j) ov[j] = (bf16)((xv[j] - mean) * rstd * sv[j] + bvv[j]);
  *(bf16x8*)(h2 + base) = ov;
}

// out = sum(parts bf16) + b2 + x2   (fp32 out); 8 elems/thread
__global__ __launch_bounds__(256) void final_comb(const bf16* __restrict__ parts, int nsplit,
                                                  const float* __restrict__ b2,
                                                  const float* __restrict__ x2,
                                                  float* __restrict__ outp) {
  const int i8 = blockIdx.x * 256 + threadIdx.x;   // 262144 total
  const size_t off = (size_t)i8 * 8;
  float acc[8];
  float4 xa = *(const float4*)(x2 + off);
  float4 xb = *(const float4*)(x2 + off + 4);
  float4 ba = *(const float4*)(b2 + (off & 511));
  float4 bb = *(const float4*)(b2 + ((off & 511) + 4));
  acc[0] = xa.x + ba.x; acc[1] = xa.y + ba.y; acc[2] = xa.z + ba.z; acc[3] = xa.w + ba.w;
  acc[4] = xb.x + bb.x; acc[5] = xb.y + bb.y; acc[6] = xb.z + bb.z; acc[7] = xb.w + bb.w;
  for (int z = 0; z < nsplit; ++z) {
    bf16x8 p = *(const bf16x8*)(parts + (size_t)z * 2097152 + off);
#pragma unroll
    for (int j = 0; j < 8; ++j) acc[j] += (float)p[j];
  }
  *(float4*)(outp + off) = make_float4(acc[0], acc[1], acc[2], acc[3]);
  *(float4*)(outp + off + 4) = make_float4(acc[4], acc[5], acc[6], acc[7]);
}

// ---------------------------------------------------------------------------
// GEMM32: 64x64 tile, 4 waves (2x2), one 32x32x16 MFMA acc per wave, BK=64.
// 3-buffer pipeline with COUNTED vmcnt (T3+T4): stage kt+2 -> compute kt ->
// s_waitcnt vmcnt(4) (never 0 mid-loop) -> raw s_barrier. The barrier gates
// the overwrite of buf[(kt+2)%3] (= buffer read in compute kt-1).
// EPI 1: +bias+res->f32   EPI 2: +bias,gelu->bf16
// EPI 3: qkv split-write q2/k2/v2 via LDS transpose (coalesced)
// ---------------------------------------------------------------------------
template <int EPI>
__global__ __launch_bounds__(256, 3) void gemm32(const bf16* __restrict__ A,
                                                 const bf16* __restrict__ Bt,
                                                 const float* __restrict__ bias,
                                                 const float* __restrict__ res,
                                                 void* __restrict__ outp,
                                                 bf16* __restrict__ k2,
                                                 bf16* __restrict__ v2,
                                                 int M, int N, int K) {
  __shared__ bf16 a_lds[3][64 * 64];
  __shared__ bf16 b_lds[3][64 * 64];
  const int m0 = blockIdx.x * 64, n0 = blockIdx.y * 64;
  const int tid = threadIdx.x, l = tid & 63, w = tid >> 6;
  const int wm = w >> 1, wn = w & 1;
  const int hi = l >> 5, l5 = l & 31;
  const int lr = l >> 3;
  const int cs = (l & 7) ^ (lr & 7);
  const int swl = l5 & 7;

  const bf16* ag = A + (size_t)(m0 + w * 16 + lr) * K + cs * 8;
  const bf16* bg = Bt + (size_t)(n0 + w * 16 + lr) * K + cs * 8;
  const size_t r8 = (size_t)8 * K;

#define GS32(B_)                                                   \
  do {                                                             \
    gload_lds16(ag,      (char*)a_lds[(B_)] + (w * 16) * 128);     \
    gload_lds16(ag + r8, (char*)a_lds[(B_)] + (w * 16 + 8) * 128); \
    gload_lds16(bg,      (char*)b_lds[(B_)] + (w * 16) * 128);     \
    gload_lds16(bg + r8, (char*)b_lds[(B_)] + (w * 16 + 8) * 128); \
    ag += 64; bg += 64;                                            \
  } while (0)

  f32x16 acc = {};
  const int kiters = K >> 6;   // >= 2 for all call sites (K in {512,2048})
  GS32(0);
  GS32(1);
  asm volatile("s_waitcnt vmcnt(4)" ::: "memory");
  __builtin_amdgcn_s_barrier();
  for (int kt = 0; kt < kiters; ++kt) {
    if (kt + 2 < kiters) GS32((kt + 2) % 3);
    const bf16* ab = a_lds[kt % 3] + (wm * 32 + l5) * 64;
    const bf16* bb = b_lds[kt % 3] + (wn * 32 + l5) * 64;
#pragma unroll
    for (int kk = 0; kk < 4; ++kk) {
      bf16x8 af = *(const bf16x8*)(ab + ((kk * 2 + hi) ^ swl) * 8);
      bf16x8 bf_ = *(const bf16x8*)(bb + ((kk * 2 + hi) ^ swl) * 8);
      acc = MFMA32(bf_, af, acc);  // A-op = Bt rows, B-op = A rows
    }
    if (kt + 1 < kiters) {
      if (kt + 2 < kiters) asm volatile("s_waitcnt vmcnt(4)" ::: "memory");
      else                 asm volatile("s_waitcnt vmcnt(0)" ::: "memory");
      __builtin_amdgcn_s_barrier();
    }
  }
#undef GS32

  const int row = m0 + wm * 32 + l5;
  if constexpr (EPI == 1 || EPI == 2) {
#pragma unroll
    for (int rg = 0; rg < 4; ++rg) {
      const int cb = n0 + wn * 32 + rg * 8 + hi * 4;
      float4 bb4 = *(const float4*)(bias + cb);
      float v[4];
      v[0] = acc[rg * 4 + 0] + bb4.x;
      v[1] = acc[rg * 4 + 1] + bb4.y;
      v[2] = acc[rg * 4 + 2] + bb4.z;
      v[3] = acc[rg * 4 + 3] + bb4.w;
      if constexpr (EPI == 1) {
        float4 rr = *(const float4*)(res + (size_t)row * N + cb);
        *(float4*)((float*)outp + (size_t)row * N + cb) =
            make_float4(v[0] + rr.x, v[1] + rr.y, v[2] + rr.z, v[3] + rr.w);
      } else {
        bf16x4 o;
#pragma unroll
        for (int e = 0; e < 4; ++e) {
          float t = -2.3022077697f * (v[e] + 0.044715f * v[e] * v[e] * v[e]);
          o[e] = (bf16)(v[e] / (1.f + fast_exp2(t)));
        }
        *(bf16x4*)((bf16*)outp + (size_t)row * N + cb) = o;
      }
    }
  } else {  // EPI 3: stash C tile in LDS, then coalesced q2/k2/v2 writes
    __syncthreads();
    bf16(*ct)[72] = (bf16(*)[72])a_lds;   // 64 x 72 bf16 = 9216 B
    const int rl = wm * 32 + l5;
#pragma unroll
    for (int rg = 0; rg < 4; ++rg) {
      const int cl = wn * 32 + rg * 8 + hi * 4;
      float4 bb4 = *(const float4*)(bias + n0 + cl);
      bf16x4 o;
      o[0] = (bf16)(acc[rg * 4 + 0] + bb4.x);
      o[1] = (bf16)(acc[rg * 4 + 1] + bb4.y);
      o[2] = (bf16)(acc[rg * 4 + 2] + bb4.z);
      o[3] = (bf16)(acc[rg * 4 + 3] + bb4.w);
      *(bf16x4*)(&ct[rl][cl]) = o;
    }
    __syncthreads();
    if (n0 < 512) {            // q2 [t][512]
#pragma unroll
      for (int p = 0; p < 2; ++p) {
        int idx = p * 256 + tid;
        int r = idx >> 3, c = (idx & 7) * 8;
        *(bf16x8*)((bf16*)outp + (size_t)(m0 + r) * 512 + n0 + c) =
            *(const bf16x8*)(&ct[r][c]);
      }
    } else if (n0 < 1024) {    // k2 [h][t][64] (tile is fully contiguous)
      bf16* kb = k2 + (size_t)((n0 - 512) >> 6) * 262144 + (size_t)m0 * 64;
#pragma unroll
      for (int p = 0; p < 2; ++p) {
        int idx = p * 256 + tid;
        int r = idx >> 3, c = (idx & 7) * 8;
        *(bf16x8*)(kb + r * 64 + c) = *(const bf16x8*)(&ct[r][c]);
      }
    } else {                   // v2 [h][panel][d][32]
      bf16* vb = v2 + (size_t)((n0 - 1024) >> 6) * 262144 + (size_t)(m0 >> 5) * 2048;
      const int d = tid >> 2, t8 = (tid & 3) * 8;
#pragma unroll
      for (int p = 0; p < 2; ++p) {
        bf16x8 vv;
#pragma unroll
        for (int e = 0; e < 8; ++e) vv[e] = ct[p * 32 + t8 + e][d];
        *(bf16x8*)(vb + p * 2048 + d * 32 + t8) = vv;
      }
    }
  }
}

// ---------------------------------------------------------------------------
// Split-K GEMM32 partial (3-buffer counted-vmcnt pipeline): parts bf16 raw
// ---------------------------------------------------------------------------
__global__ __launch_bounds__(256, 3) void gemm32_skp(const bf16* __restrict__ A,
                                                     const bf16* __restrict__ Bt,
                                                     bf16* __restrict__ parts,
                                                     int M, int N, int Kstride, int Kc) {
  __shared__ bf16 a_lds[3][64 * 64];
  __shared__ bf16 b_lds[3][64 * 64];
  const int m0 = blockIdx.x * 64, n0 = blockIdx.y * 64, kz = blockIdx.z;
  A += (size_t)kz * Kc;
  Bt += (size_t)kz * Kc;
  bf16* outp = parts + (size_t)kz * M * N;
  const int tid = threadIdx.x, l = tid & 63, w = tid >> 6;
  const int wm = w >> 1, wn = w & 1;
  const int hi = l >> 5, l5 = l & 31;
  const int lr = l >> 3;
  const int cs = (l & 7) ^ (lr & 7);
  const int swl = l5 & 7;

  const bf16* ag = A + (size_t)(m0 + w * 16 + lr) * Kstride + cs * 8;
  const bf16* bg = Bt + (size_t)(n0 + w * 16 + lr) * Kstride + cs * 8;
  const size_t r8 = (size_t)8 * Kstride;

#define GS32(B_)                                                   \
  do {                                                             \
    gload_lds16(ag,      (char*)a_lds[(B_)] + (w * 16) * 128);     \
    gload_lds16(ag + r8, (char*)a_lds[(B_)] + (w * 16 + 8) * 128); \
    gload_lds16(bg,      (char*)b_lds[(B_)] + (w * 16) * 128);     \
    gload_lds16(bg + r8, (char*)b_lds[(B_)] + (w * 16 + 8) * 128); \
    ag += 64; bg += 64;                                            \
  } while (0)

  f32x16 acc = {};
  const int kiters = Kc >> 6;   // 4 or 8
  GS32(0);
  GS32(1);
  asm volatile("s_waitcnt vmcnt(4)" ::: "memory");
  __builtin_amdgcn_s_barrier();
  for (int kt = 0; kt < kiters; ++kt) {
    if (kt + 2 < kiters) GS32((kt + 2) % 3);
    const bf16* ab = a_lds[kt % 3] + (wm * 32 + l5) * 64;
    const bf16* bb = b_lds[kt % 3] + (wn * 32 + l5) * 64;
#pragma unroll
    for (int kk = 0; kk < 4; ++kk) {
      bf16x8 af = *(const bf16x8*)(ab + ((kk * 2 + hi) ^ swl) * 8);
      bf16x8 bf_ = *(const bf16x8*)(bb + ((kk * 2 + hi) ^ swl) * 8);
      acc = MFMA32(bf_, af, acc);
    }
    if (kt + 1 < kiters) {
      if (kt + 2 < kiters) asm volatile("s_waitcnt vmcnt(4)" ::: "memory");
      else                 asm volatile("s_waitcnt vmcnt(0)" ::: "memory");
      __builtin_amdgcn_s_barrier();
    }
  }
#undef GS32

  const int row = m0 + wm * 32 + l5;
#pragma unroll
  for (int rg = 0; rg < 4; ++rg) {
    const int cb = n0 + wn * 32 + rg * 8 + hi * 4;
    bf16x4 o;
#pragma unroll
    for (int e = 0; e < 4; ++e) o[e] = (bf16)acc[rg * 4 + e];
    *(bf16x4*)(outp + (size_t)row * N + cb) = o;
  }
}

// ---------------------------------------------------------------------------
// Flash attention v8: 8 waves/block (512 thr), grid 512 = qt(64) x head(8).
// pair = w>>1 (4 key-quarters of 1024), wq = w&1 (32-q-row half). Main loop
// identical to the measured 52us v7 (LDS dbuf staging from dense k2/v2,
// one barrier/tile, constant-max in-register softmax, raw v_exp2, permlane
// pack). In-block 4-way combine via LDS; writes final attnb directly
// (no opart/lpart, no attn_comb kernel). LDS 64KB -> 2 blocks/CU.
// ---------------------------------------------------------------------------
__global__ __launch_bounds__(512, 4) void attn_k(const bf16* __restrict__ q2,
                                                 const bf16* __restrict__ k2,
                                                 const bf16* __restrict__ v2,
                                                 bf16* __restrict__ attnb) {
  const int bid = blockIdx.x;
  const int head = bid & 7;          // one head per XCD (L2 locality)
  const int qt = bid >> 3;
  const int w = threadIdx.x >> 6, l = threadIdx.x & 63;
  const int hi = l >> 5, l5 = l & 31;
  const int pair = w >> 1, wq = w & 1;

  __shared__ __align__(16) char smem[65536];
  char* kt_l = smem + pair * 16384;   // [2][4096] B
  char* vt_l = kt_l + 8192;           // [2][4096] B

  const int qrow0 = qt * 64 + wq * 32;
  const bf16* qb = q2 + (size_t)(qrow0 + l5) * 512 + head * 64;
  bf16x8 qf[4];
#pragma unroll
  for (int cc = 0; cc < 4; ++cc) qf[cc] = *(const bf16x8*)(qb + cc * 16 + hi * 8);

  const int kstart = pair * 1024;

  const int lr = l >> 3;
  const int lc3 = (l & 7) ^ lr;
  const char* kg = (const char*)k2 + (size_t)head * 524288 + (size_t)kstart * 128 +
                   (wq * 16 + lr) * 128 + lc3 * 16;
  const char* vg = (const char*)v2 + (size_t)head * 524288 + (size_t)(kstart >> 5) * 4096 +
                   (lc3 >> 2) * 2048 + (wq * 16 + lr) * 64 + (lc3 & 3) * 16;
  const int kdst = wq * 2048;

#define STAGE(B_)                                                            \
  do {                                                                       \
    gload_lds16(kg,        kt_l + (B_) * 4096 + kdst);                       \
    gload_lds16(kg + 1024, kt_l + (B_) * 4096 + kdst + 1024);                \
    gload_lds16(vg,        vt_l + (B_) * 4096 + kdst);                       \
    gload_lds16(vg + 512,  vt_l + (B_) * 4096 + kdst + 1024);                \
    kg += 4096; vg += 4096;                                                  \
  } while (0)

  STAGE(0);
  __syncthreads();

  f32x16 o0 = {}, o1 = {};
  float psum = 0.f;
  const int swl = l5 & 7;
  const char* kbase = kt_l + l5 * 128;
  const char* vbase = vt_l + l5 * 128;

  for (int t = 0; t < 32; ++t) {
    const int cur = t & 1;
    if (t < 31) STAGE(cur ^ 1);

    __builtin_amdgcn_s_setprio(1);
    f32x16 s = {};
#pragma unroll
    for (int cc = 0; cc < 4; ++cc) {
      bf16x8 kf = *(const bf16x8*)(kbase + cur * 4096 + ((cc * 2 + hi) ^ swl) * 16);
      s = MFMA32(kf, qf[cc], s);
    }
    __builtin_amdgcn_s_setprio(0);

#pragma unroll
    for (int c = 0; c < 2; ++c) {
      float p[8];
#pragma unroll
      for (int j = 0; j < 8; ++j) p[j] = fast_exp2(s[c * 8 + j]);
      psum += ((p[0] + p[1]) + (p[2] + p[3])) + ((p[4] + p[5]) + (p[6] + p[7]));
      unsigned X = pk2(p[0], p[1]), X2 = pk2(p[2], p[3]);
      unsigned Y = pk2(p[4], p[5]), Y2 = pk2(p[6], p[7]);
      asm volatile("v_permlane32_swap_b32 %0, %1" : "+v"(X), "+v"(Y));
      asm volatile("v_permlane32_swap_b32 %0, %1" : "+v"(X2), "+v"(Y2));
      union { unsigned wd[4]; bf16x8 v; } pa;
      pa.wd[0] = X; pa.wd[1] = X2; pa.wd[2] = Y; pa.wd[3] = Y2;
      bf16x8 vf0 = *(const bf16x8*)(vbase + cur * 4096 + ((c * 2 + hi) ^ swl) * 16);
      bf16x8 vf1 = *(const bf16x8*)(vbase + cur * 4096 + ((4 + c * 2 + hi) ^ swl) * 16);
      __builtin_amdgcn_s_setprio(1);
      o0 = MFMA32(vf0, pa.v, o0);
      o1 = MFMA32(vf1, pa.v, o1);
      __builtin_amdgcn_s_setprio(0);
    }
    __syncthreads();
  }
#undef STAGE

  // 4-way key-range combine via LDS (tiles dead). 6 slots x 64 x 33 f32.
  float* comb = (float*)smem;
  if (pair > 0) {
    float* cb = comb + (((pair - 1) * 2 + wq) * 64 + l) * 33;
#pragma unroll
    for (int r = 0; r < 16; ++r) { cb[r] = o0[r]; cb[16 + r] = o1[r]; }
    cb[32] = psum;
  }
  __syncthreads();
  if (pair == 0) {
#pragma unroll
    for (int p = 0; p < 3; ++p) {
      const float* cb = comb + ((p * 2 + wq) * 64 + l) * 33;
#pragma unroll
      for (int r = 0; r < 16; ++r) { o0[r] += cb[r]; o1[r] += cb[16 + r]; }
      psum += cb[32];
    }
    const float lsum = psum + __shfl_xor(psum, 32);
    const float inv = 1.f / lsum;
    bf16* ob = attnb + (size_t)(qrow0 + l5) * 512 + head * 64;
#pragma unroll
    for (int dt = 0; dt < 2; ++dt)
#pragma unroll
      for (int rg = 0; rg < 4; ++rg) {
        bf16x4 vv;
#pragma unroll
        for (int e = 0; e < 4; ++e) {
          const float ov = (dt == 0) ? o0[rg * 4 + e] : o1[rg * 4 + e];
          vv[e] = (bf16)(ov * inv);
        }
        *(bf16x4*)(ob + dt * 32 + rg * 8 + hi * 4) = vv;
      }
  }
}

// ---------------------------------------------------------------------------
extern "C" void kernel_launch(void* const* d_in, const int* in_sizes, int n_in,
                              void* d_out, int out_size, void* d_ws, size_t ws_size,
                              hipStream_t stream) {
  const float* x    = (const float*)d_in[0];
  const float* ln1s = (const float*)d_in[1];
  const float* ln1b = (const float*)d_in[2];
  const float* Wq   = (const float*)d_in[3];
  const float* bq   = (const float*)d_in[4];
  const float* Wk   = (const float*)d_in[5];
  const float* bk   = (const float*)d_in[6];
  const float* Wv   = (const float*)d_in[7];
  const float* bv   = (const float*)d_in[8];
  const float* Wo   = (const float*)d_in[9];
  const float* bo   = (const float*)d_in[10];
  const float* ln2s = (const float*)d_in[11];
  const float* ln2b = (const float*)d_in[12];
  const float* W1   = (const float*)d_in[13];
  const float* b1   = (const float*)d_in[14];
  const float* W2   = (const float*)d_in[15];
  const float* b2   = (const float*)d_in[16];
  float* out = (float*)d_out;

  char* ws = (char*)d_ws;
  bf16*  wqkvT = (bf16*)(ws + 0);          // [1536][512] 1.5M
  bf16*  woT   = (bf16*)(ws + 1572864);    // [512][512]  0.5M
  bf16*  w1T   = (bf16*)(ws + 2097152);    // [2048][512] 2M
  bf16*  w2T   = (bf16*)(ws + 4194304);    // [512][2048] 2M
  float* bqkv  = (float*)(ws + 6291456);   // -> 6297600
  float* x2    = (float*)(ws + 6297600);   // [4096][512] f32 8M -> 14686208
  bf16*  h     = (bf16*)(ws + 14686208);   // 4M -> 18880512 (h / attnb / h2)
  bf16*  q2    = (bf16*)(ws + 18880512);   // 4M -> 23074816
  bf16*  k2    = (bf16*)(ws + 23074816);   // 4M -> 27269120
  bf16*  v2    = (bf16*)(ws + 27269120);   // 4M -> 31463424
  bf16*  attnb = h;
  bf16*  h2    = h;
  bf16*  wop   = (bf16*)(ws + 18880512);   // 2x4M bf16 over dead q2/k2
  bf16*  gbuf  = (bf16*)(ws + 18880512);   // ffn1 out 16M over dead wop/q2..v2
  bf16*  f2p   = (bf16*)(ws + 35657728);   // gated bf16 partials
  const size_t need4 = 35657728 + 4ull * 4194304;
  const size_t need2 = 35657728 + 2ull * 4194304;

  prep_ln<<<1798, 256, 0, stream>>>(Wq, Wk, Wv, Wo, W1, W2, bq, bk, bv,
                                    wqkvT, woT, w1T, w2T, bqkv, x, ln1s, ln1b, h);
  gemm32<3><<<dim3(64, 24), 256, 0, stream>>>(h, wqkvT, bqkv, nullptr, q2, k2, v2,
                                              4096, 1536, 512);
  attn_k<<<512, 512, 0, stream>>>(q2, k2, v2, attnb);
  gemm32_skp<<<dim3(64, 8, 2), 256, 0, stream>>>(attnb, woT, wop, 4096, 512, 512, 256);
  ln2_comb<<<1024, 256, 0, stream>>>(wop, wop + 2097152, x, bo, ln2s, ln2b, x2, h2);
  gemm32<2><<<dim3(64, 32), 256, 0, stream>>>(h2, w1T, b1, nullptr, gbuf, nullptr, nullptr,
                                              4096, 2048, 512);
  if (ws_size >= need4) {
    gemm32_skp<<<dim3(64, 8, 4), 256, 0, stream>>>(gbuf, w2T, f2p, 4096, 512, 2048, 512);
    final_comb<<<1024, 256, 0, stream>>>(f2p, 4, b2, x2, out);
  } else if (ws_size >= need2) {
    gemm32_skp<<<dim3(64, 8, 2), 256, 0, stream>>>(gbuf, w2T, f2p, 4096, 512, 2048, 1024);
    final_comb<<<1024, 256, 0, stream>>>(f2p, 2, b2, x2, out);
  } else {
    gemm32<1><<<dim3(64, 8), 256, 0, stream>>>(gbuf, w2T, b2, x2, out, nullptr, nullptr,
                                               4096, 512, 2048);
  }
}

// Round 11
// 140.199 us; speedup vs baseline: 1.0753x; 1.0473x over previous
//
#include <hip/hip_runtime.h>
#include <hip/hip_bf16.h>
#include <stdint.h>

typedef __bf16 bf16;
typedef __bf16 bf16x4 __attribute__((ext_vector_type(4)));
typedef __bf16 bf16x8 __attribute__((ext_vector_type(8)));
typedef float  f32x4  __attribute__((ext_vector_type(4)));
typedef float  f32x16 __attribute__((ext_vector_type(16)));

#define MFMA32(A_, B_, C_) __builtin_amdgcn_mfma_f32_32x32x16_bf16((A_), (B_), (C_), 0, 0, 0)

#define QSCALE 0.1803368801111137f  // 0.125 * log2(e), folded into Wq/bq

__device__ __forceinline__ void gload_lds16(const void* g, void* l) {
  __builtin_amdgcn_global_load_lds(
      (const __attribute__((address_space(1))) unsigned int*)g,
      (__attribute__((address_space(3))) unsigned int*)l, 16, 0, 0);
}

__device__ __forceinline__ unsigned pk2(float lo, float hi_) {
  union { bf16 h[2]; unsigned u; } t;
  t.h[0] = (bf16)lo; t.h[1] = (bf16)hi_;
  return t.u;
}

__device__ __forceinline__ float fast_exp2(float x) {
#if __has_builtin(__builtin_amdgcn_exp2f)
  return __builtin_amdgcn_exp2f(x);
#else
  return exp2f(x);
#endif
}

// ---------------------------------------------------------------------------
// prep_ln: blocks 0..773 = weight transposes + bias pack; 774..1797 = LN1.
// ---------------------------------------------------------------------------
__global__ __launch_bounds__(256) void prep_ln(const float* __restrict__ Wq,
                                               const float* __restrict__ Wk,
                                               const float* __restrict__ Wv,
                                               const float* __restrict__ Wo,
                                               const float* __restrict__ W1,
                                               const float* __restrict__ W2,
                                               const float* __restrict__ bq,
                                               const float* __restrict__ bk,
                                               const float* __restrict__ bv,
                                               bf16* __restrict__ wqkvT, bf16* __restrict__ woT,
                                               bf16* __restrict__ w1T, bf16* __restrict__ w2T,
                                               float* __restrict__ bqkv,
                                               const float* __restrict__ x,
                                               const float* __restrict__ ln1s,
                                               const float* __restrict__ ln1b,
                                               bf16* __restrict__ h) {
  const int b = blockIdx.x;
  if (b >= 774) {  // ---- LayerNorm rows ----
    const int w = threadIdx.x >> 6, l = threadIdx.x & 63;
    const int row = (b - 774) * 4 + w;
    const float4* xp = (const float4*)(x + (size_t)row * 512 + l * 8);
    float4 v0 = xp[0], v1 = xp[1];
    float xv[8] = {v0.x, v0.y, v0.z, v0.w, v1.x, v1.y, v1.z, v1.w};
    float s = 0.f, q = 0.f;
#pragma unroll
    for (int j = 0; j < 8; ++j) { s += xv[j]; q += xv[j] * xv[j]; }
#pragma unroll
    for (int m = 1; m < 64; m <<= 1) { s += __shfl_xor(s, m); q += __shfl_xor(q, m); }
    const float mean = s * (1.f / 512.f);
    const float var = q * (1.f / 512.f) - mean * mean;
    const float rstd = rsqrtf(var + 1e-6f);
    const float4* scp = (const float4*)(ln1s + l * 8);
    const float4* bip = (const float4*)(ln1b + l * 8);
    float4 s0 = scp[0], s1 = scp[1], b0 = bip[0], b1 = bip[1];
    float sv[8] = {s0.x, s0.y, s0.z, s0.w, s1.x, s1.y, s1.z, s1.w};
    float bvv[8] = {b0.x, b0.y, b0.z, b0.w, b1.x, b1.y, b1.z, b1.w};
    bf16x8 ov;
#pragma unroll
    for (int j = 0; j < 8; ++j) ov[j] = (bf16)((xv[j] - mean) * rstd * sv[j] + bvv[j]);
    *(bf16x8*)(h + (size_t)row * 512 + l * 8) = ov;
    return;
  }
  if (b >= 768) {  // ---- bias pack ----
    int i = (b - 768) * 256 + threadIdx.x;
    if (i < 1536)
      bqkv[i] = (i < 512) ? bq[i] * QSCALE : (i < 1024 ? bk[i - 512] : bv[i - 1024]);
    return;
  }
  const float* in; bf16* outp; int K, N, t; float sc = 1.f;
  if (b < 64)       { in = Wq; outp = wqkvT;              K = 512;  N = 512;  t = b;       sc = QSCALE; }
  else if (b < 128) { in = Wk; outp = wqkvT + 512 * 512;  K = 512;  N = 512;  t = b - 64;  }
  else if (b < 192) { in = Wv; outp = wqkvT + 1024 * 512; K = 512;  N = 512;  t = b - 128; }
  else if (b < 256) { in = Wo; outp = woT;                K = 512;  N = 512;  t = b - 192; }
  else if (b < 512) { in = W1; outp = w1T;                K = 512;  N = 2048; t = b - 256; }
  else              { in = W2; outp = w2T;                K = 2048; N = 512;  t = b - 512; }
  const int tx = K >> 6;
  const int k0 = (t % tx) * 64, n0 = (t / tx) * 64;
  __shared__ bf16 tile[64][72];
  const int tid = threadIdx.x;
#pragma unroll
  for (int s = 0; s < 16; ++s) {
    int j = tid + s * 256;
    int r = j >> 6, c = j & 63;
    tile[r][c] = (bf16)(in[(size_t)(k0 + r) * N + n0 + c] * sc);
  }
  __syncthreads();
#pragma unroll
  for (int s = 0; s < 16; ++s) {
    int j = tid + s * 256;
    int n = j >> 6, k = j & 63;
    outp[(size_t)(n0 + n) * K + k0 + k] = tile[k][n];
  }
}

// ---------------------------------------------------------------------------
// ln_k: pure LayerNorm, x2 fp32 [4096][512] -> h2 bf16. One wave per row.
// ---------------------------------------------------------------------------
__global__ __launch_bounds__(256) void ln_k(const float* __restrict__ x,
                                            const float* __restrict__ sc,
                                            const float* __restrict__ bi,
                                            bf16* __restrict__ out) {
  const int w = threadIdx.x >> 6, l = threadIdx.x & 63;
  const int row = blockIdx.x * 4 + w;
  const float4* xp = (const float4*)(x + (size_t)row * 512 + l * 8);
  float4 v0 = xp[0], v1 = xp[1];
  float xv[8] = {v0.x, v0.y, v0.z, v0.w, v1.x, v1.y, v1.z, v1.w};
  float s = 0.f, q = 0.f;
#pragma unroll
  for (int j = 0; j < 8; ++j) { s += xv[j]; q += xv[j] * xv[j]; }
#pragma unroll
  for (int m = 1; m < 64; m <<= 1) { s += __shfl_xor(s, m); q += __shfl_xor(q, m); }
  const float mean = s * (1.f / 512.f);
  const float var = q * (1.f / 512.f) - mean * mean;
  const float rstd = rsqrtf(var + 1e-6f);
  const float4* scp = (const float4*)(sc + l * 8);
  const float4* bip = (const float4*)(bi + l * 8);
  float4 s0 = scp[0], s1 = scp[1], b0 = bip[0], b1 = bip[1];
  float sv[8] = {s0.x, s0.y, s0.z, s0.w, s1.x, s1.y, s1.z, s1.w};
  float bvv[8] = {b0.x, b0.y, b0.z, b0.w, b1.x, b1.y, b1.z, b1.w};
  bf16x8 ov;
#pragma unroll
  for (int j = 0; j < 8; ++j) ov[j] = (bf16)((xv[j] - mean) * rstd * sv[j] + bvv[j]);
  *(bf16x8*)(out + (size_t)row * 512 + l * 8) = ov;
}

// ---------------------------------------------------------------------------
// GEMM32: 64x64 tile, 4 waves (2x2), one 32x32x16 MFMA acc per wave, BK=64.
// 3-buffer pipeline with COUNTED vmcnt (T3+T4): stage kt+2 -> compute kt ->
// s_waitcnt vmcnt(4) (never 0 mid-loop) -> raw s_barrier.
// EPI 1: +bias+res(f32)->f32   EPI 2: +bias,gelu->bf16
// EPI 3: qkv split-write q2/k2/v2 via LDS transpose (coalesced)
// ---------------------------------------------------------------------------
template <int EPI>
__global__ __launch_bounds__(256, 3) void gemm32(const bf16* __restrict__ A,
                                                 const bf16* __restrict__ Bt,
                                                 const float* __restrict__ bias,
                                                 const float* __restrict__ res,
                                                 void* __restrict__ outp,
                                                 bf16* __restrict__ k2,
                                                 bf16* __restrict__ v2,
                                                 int M, int N, int K) {
  __shared__ bf16 a_lds[3][64 * 64];
  __shared__ bf16 b_lds[3][64 * 64];
  const int m0 = blockIdx.x * 64, n0 = blockIdx.y * 64;
  const int tid = threadIdx.x, l = tid & 63, w = tid >> 6;
  const int wm = w >> 1, wn = w & 1;
  const int hi = l >> 5, l5 = l & 31;
  const int lr = l >> 3;
  const int cs = (l & 7) ^ (lr & 7);
  const int swl = l5 & 7;

  const bf16* ag = A + (size_t)(m0 + w * 16 + lr) * K + cs * 8;
  const bf16* bg = Bt + (size_t)(n0 + w * 16 + lr) * K + cs * 8;
  const size_t r8 = (size_t)8 * K;

#define GS32(B_)                                                   \
  do {                                                             \
    gload_lds16(ag,      (char*)a_lds[(B_)] + (w * 16) * 128);     \
    gload_lds16(ag + r8, (char*)a_lds[(B_)] + (w * 16 + 8) * 128); \
    gload_lds16(bg,      (char*)b_lds[(B_)] + (w * 16) * 128);     \
    gload_lds16(bg + r8, (char*)b_lds[(B_)] + (w * 16 + 8) * 128); \
    ag += 64; bg += 64;                                            \
  } while (0)

  f32x16 acc = {};
  const int kiters = K >> 6;   // >= 2 for all call sites
  GS32(0);
  GS32(1);
  asm volatile("s_waitcnt vmcnt(4)" ::: "memory");
  __builtin_amdgcn_s_barrier();
  for (int kt = 0; kt < kiters; ++kt) {
    if (kt + 2 < kiters) GS32((kt + 2) % 3);
    const bf16* ab = a_lds[kt % 3] + (wm * 32 + l5) * 64;
    const bf16* bb = b_lds[kt % 3] + (wn * 32 + l5) * 64;
#pragma unroll
    for (int kk = 0; kk < 4; ++kk) {
      bf16x8 af = *(const bf16x8*)(ab + ((kk * 2 + hi) ^ swl) * 8);
      bf16x8 bf_ = *(const bf16x8*)(bb + ((kk * 2 + hi) ^ swl) * 8);
      acc = MFMA32(bf_, af, acc);  // A-op = Bt rows, B-op = A rows
    }
    if (kt + 1 < kiters) {
      if (kt + 2 < kiters) asm volatile("s_waitcnt vmcnt(4)" ::: "memory");
      else                 asm volatile("s_waitcnt vmcnt(0)" ::: "memory");
      __builtin_amdgcn_s_barrier();
    }
  }
#undef GS32

  const int row = m0 + wm * 32 + l5;
  if constexpr (EPI == 1 || EPI == 2) {
#pragma unroll
    for (int rg = 0; rg < 4; ++rg) {
      const int cb = n0 + wn * 32 + rg * 8 + hi * 4;
      float4 bb4 = *(const float4*)(bias + cb);
      float v[4];
      v[0] = acc[rg * 4 + 0] + bb4.x;
      v[1] = acc[rg * 4 + 1] + bb4.y;
      v[2] = acc[rg * 4 + 2] + bb4.z;
      v[3] = acc[rg * 4 + 3] + bb4.w;
      if constexpr (EPI == 1) {
        float4 rr = *(const float4*)(res + (size_t)row * N + cb);
        *(float4*)((float*)outp + (size_t)row * N + cb) =
            make_float4(v[0] + rr.x, v[1] + rr.y, v[2] + rr.z, v[3] + rr.w);
      } else {
        bf16x4 o;
#pragma unroll
        for (int e = 0; e < 4; ++e) {
          float t = -2.3022077697f * (v[e] + 0.044715f * v[e] * v[e] * v[e]);
          o[e] = (bf16)(v[e] / (1.f + fast_exp2(t)));
        }
        *(bf16x4*)((bf16*)outp + (size_t)row * N + cb) = o;
      }
    }
  } else {  // EPI 3: stash C tile in LDS, then coalesced q2/k2/v2 writes
    __syncthreads();
    bf16(*ct)[72] = (bf16(*)[72])a_lds;   // 64 x 72 bf16 = 9216 B
    const int rl = wm * 32 + l5;
#pragma unroll
    for (int rg = 0; rg < 4; ++rg) {
      const int cl = wn * 32 + rg * 8 + hi * 4;
      float4 bb4 = *(const float4*)(bias + n0 + cl);
      bf16x4 o;
      o[0] = (bf16)(acc[rg * 4 + 0] + bb4.x);
      o[1] = (bf16)(acc[rg * 4 + 1] + bb4.y);
      o[2] = (bf16)(acc[rg * 4 + 2] + bb4.z);
      o[3] = (bf16)(acc[rg * 4 + 3] + bb4.w);
      *(bf16x4*)(&ct[rl][cl]) = o;
    }
    __syncthreads();
    if (n0 < 512) {            // q2 [t][512]
#pragma unroll
      for (int p = 0; p < 2; ++p) {
        int idx = p * 256 + tid;
        int r = idx >> 3, c = (idx & 7) * 8;
        *(bf16x8*)((bf16*)outp + (size_t)(m0 + r) * 512 + n0 + c) =
            *(const bf16x8*)(&ct[r][c]);
      }
    } else if (n0 < 1024) {    // k2 [h][t][64] (tile fully contiguous)
      bf16* kb = k2 + (size_t)((n0 - 512) >> 6) * 262144 + (size_t)m0 * 64;
#pragma unroll
      for (int p = 0; p < 2; ++p) {
        int idx = p * 256 + tid;
        int r = idx >> 3, c = (idx & 7) * 8;
        *(bf16x8*)(kb + r * 64 + c) = *(const bf16x8*)(&ct[r][c]);
      }
    } else {                   // v2 [h][panel][d][32]
      bf16* vb = v2 + (size_t)((n0 - 1024) >> 6) * 262144 + (size_t)(m0 >> 5) * 2048;
      const int d = tid >> 2, t8 = (tid & 3) * 8;
#pragma unroll
      for (int p = 0; p < 2; ++p) {
        bf16x8 vv;
#pragma unroll
        for (int e = 0; e < 8; ++e) vv[e] = ct[p * 32 + t8 + e][d];
        *(bf16x8*)(vb + p * 2048 + d * 32 + t8) = vv;
      }
    }
  }
}

// ---------------------------------------------------------------------------
// Flash attention v8 (frozen at measured 52us): 8 waves/block, grid 512 =
// qt(64) x head(8). pair = w>>1 (4 key-quarters of 1024), wq = w&1 (32-q-row
// half). LDS dbuf staging from dense k2/v2, one barrier/tile, constant-max
// in-register softmax, raw v_exp2, permlane pack. In-block 4-way combine.
// ---------------------------------------------------------------------------
__global__ __launch_bounds__(512, 4) void attn_k(const bf16* __restrict__ q2,
                                                 const bf16* __restrict__ k2,
                                                 const bf16* __restrict__ v2,
                                                 bf16* __restrict__ attnb) {
  const int bid = blockIdx.x;
  const int head = bid & 7;          // one head per XCD (L2 locality)
  const int qt = bid >> 3;
  const int w = threadIdx.x >> 6, l = threadIdx.x & 63;
  const int hi = l >> 5, l5 = l & 31;
  const int pair = w >> 1, wq = w & 1;

  __shared__ __align__(16) char smem[65536];
  char* kt_l = smem + pair * 16384;   // [2][4096] B
  char* vt_l = kt_l + 8192;           // [2][4096] B

  const int qrow0 = qt * 64 + wq * 32;
  const bf16* qb = q2 + (size_t)(qrow0 + l5) * 512 + head * 64;
  bf16x8 qf[4];
#pragma unroll
  for (int cc = 0; cc < 4; ++cc) qf[cc] = *(const bf16x8*)(qb + cc * 16 + hi * 8);

  const int kstart = pair * 1024;

  const int lr = l >> 3;
  const int lc3 = (l & 7) ^ lr;
  const char* kg = (const char*)k2 + (size_t)head * 524288 + (size_t)kstart * 128 +
                   (wq * 16 + lr) * 128 + lc3 * 16;
  const char* vg = (const char*)v2 + (size_t)head * 524288 + (size_t)(kstart >> 5) * 4096 +
                   (lc3 >> 2) * 2048 + (wq * 16 + lr) * 64 + (lc3 & 3) * 16;
  const int kdst = wq * 2048;

#define STAGE(B_)                                                            \
  do {                                                                       \
    gload_lds16(kg,        kt_l + (B_) * 4096 + kdst);                       \
    gload_lds16(kg + 1024, kt_l + (B_) * 4096 + kdst + 1024);                \
    gload_lds16(vg,        vt_l + (B_) * 4096 + kdst);                       \
    gload_lds16(vg + 512,  vt_l + (B_) * 4096 + kdst + 1024);                \
    kg += 4096; vg += 4096;                                                  \
  } while (0)

  STAGE(0);
  __syncthreads();

  f32x16 o0 = {}, o1 = {};
  float psum = 0.f;
  const int swl = l5 & 7;
  const char* kbase = kt_l + l5 * 128;
  const char* vbase = vt_l + l5 * 128;

  for (int t = 0; t < 32; ++t) {
    const int cur = t & 1;
    if (t < 31) STAGE(cur ^ 1);

    __builtin_amdgcn_s_setprio(1);
    f32x16 s = {};
#pragma unroll
    for (int cc = 0; cc < 4; ++cc) {
      bf16x8 kf = *(const bf16x8*)(kbase + cur * 4096 + ((cc * 2 + hi) ^ swl) * 16);
      s = MFMA32(kf, qf[cc], s);
    }
    __builtin_amdgcn_s_setprio(0);

#pragma unroll
    for (int c = 0; c < 2; ++c) {
      float p[8];
#pragma unroll
      for (int j = 0; j < 8; ++j) p[j] = fast_exp2(s[c * 8 + j]);
      psum += ((p[0] + p[1]) + (p[2] + p[3])) + ((p[4] + p[5]) + (p[6] + p[7]));
      unsigned X = pk2(p[0], p[1]), X2 = pk2(p[2], p[3]);
      unsigned Y = pk2(p[4], p[5]), Y2 = pk2(p[6], p[7]);
      asm volatile("v_permlane32_swap_b32 %0, %1" : "+v"(X), "+v"(Y));
      asm volatile("v_permlane32_swap_b32 %0, %1" : "+v"(X2), "+v"(Y2));
      union { unsigned wd[4]; bf16x8 v; } pa;
      pa.wd[0] = X; pa.wd[1] = X2; pa.wd[2] = Y; pa.wd[3] = Y2;
      bf16x8 vf0 = *(const bf16x8*)(vbase + cur * 4096 + ((c * 2 + hi) ^ swl) * 16);
      bf16x8 vf1 = *(const bf16x8*)(vbase + cur * 4096 + ((4 + c * 2 + hi) ^ swl) * 16);
      __builtin_amdgcn_s_setprio(1);
      o0 = MFMA32(vf0, pa.v, o0);
      o1 = MFMA32(vf1, pa.v, o1);
      __builtin_amdgcn_s_setprio(0);
    }
    __syncthreads();
  }
#undef STAGE

  // 4-way key-range combine via LDS (tiles dead). 6 slots x 64 x 33 f32.
  float* comb = (float*)smem;
  if (pair > 0) {
    float* cb = comb + (((pair - 1) * 2 + wq) * 64 + l) * 33;
#pragma unroll
    for (int r = 0; r < 16; ++r) { cb[r] = o0[r]; cb[16 + r] = o1[r]; }
    cb[32] = psum;
  }
  __syncthreads();
  if (pair == 0) {
#pragma unroll
    for (int p = 0; p < 3; ++p) {
      const float* cb = comb + ((p * 2 + wq) * 64 + l) * 33;
#pragma unroll
      for (int r = 0; r < 16; ++r) { o0[r] += cb[r]; o1[r] += cb[16 + r]; }
      psum += cb[32];
    }
    const float lsum = psum + __shfl_xor(psum, 32);
    const float inv = 1.f / lsum;
    bf16* ob = attnb + (size_t)(qrow0 + l5) * 512 + head * 64;
#pragma unroll
    for (int dt = 0; dt < 2; ++dt)
#pragma unroll
      for (int rg = 0; rg < 4; ++rg) {
        bf16x4 vv;
#pragma unroll
        for (int e = 0; e < 4; ++e) {
          const float ov = (dt == 0) ? o0[rg * 4 + e] : o1[rg * 4 + e];
          vv[e] = (bf16)(ov * inv);
        }
        *(bf16x4*)(ob + dt * 32 + rg * 8 + hi * 4) = vv;
      }
  }
}

// ---------------------------------------------------------------------------
extern "C" void kernel_launch(void* const* d_in, const int* in_sizes, int n_in,
                              void* d_out, int out_size, void* d_ws, size_t ws_size,
                              hipStream_t stream) {
  const float* x    = (const float*)d_in[0];
  const float* ln1s = (const float*)d_in[1];
  const float* ln1b = (const float*)d_in[2];
  const float* Wq   = (const float*)d_in[3];
  const float* bq   = (const float*)d_in[4];
  const float* Wk   = (const float*)d_in[5];
  const float* bk   = (const float*)d_in[6];
  const float* Wv   = (const float*)d_in[7];
  const float* bv   = (const float*)d_in[8];
  const float* Wo   = (const float*)d_in[9];
  const float* bo   = (const float*)d_in[10];
  const float* ln2s = (const float*)d_in[11];
  const float* ln2b = (const float*)d_in[12];
  const float* W1   = (const float*)d_in[13];
  const float* b1   = (const float*)d_in[14];
  const float* W2   = (const float*)d_in[15];
  const float* b2   = (const float*)d_in[16];
  float* out = (float*)d_out;

  char* ws = (char*)d_ws;
  bf16*  wqkvT = (bf16*)(ws + 0);          // [1536][512] 1.5M
  bf16*  woT   = (bf16*)(ws + 1572864);    // [512][512]  0.5M
  bf16*  w1T   = (bf16*)(ws + 2097152);    // [2048][512] 2M
  bf16*  w2T   = (bf16*)(ws + 4194304);    // [512][2048] 2M
  float* bqkv  = (float*)(ws + 6291456);   // -> 6297600
  float* x2    = (float*)(ws + 6297600);   // [4096][512] f32 8M -> 14686208
  bf16*  h     = (bf16*)(ws + 14686208);   // 4M -> 18880512 (h / attnb / h2)
  bf16*  q2    = (bf16*)(ws + 18880512);   // 4M -> 23074816
  bf16*  k2    = (bf16*)(ws + 23074816);   // 4M -> 27269120
  bf16*  v2    = (bf16*)(ws + 27269120);   // 4M -> 31463424
  bf16*  attnb = h;
  bf16*  h2    = h;
  bf16*  gbuf  = (bf16*)(ws + 18880512);   // ffn1 out 16M over dead q2/k2/v2

  prep_ln<<<1798, 256, 0, stream>>>(Wq, Wk, Wv, Wo, W1, W2, bq, bk, bv,
                                    wqkvT, woT, w1T, w2T, bqkv, x, ln1s, ln1b, h);
  gemm32<3><<<dim3(64, 24), 256, 0, stream>>>(h, wqkvT, bqkv, nullptr, q2, k2, v2,
                                              4096, 1536, 512);
  attn_k<<<512, 512, 0, stream>>>(q2, k2, v2, attnb);
  // wo projection: x2 = attnb @ Wo^T + bo + x   (direct, no split-K)
  gemm32<1><<<dim3(64, 8), 256, 0, stream>>>(attnb, woT, bo, x, x2, nullptr, nullptr,
                                             4096, 512, 512);
  ln_k<<<1024, 256, 0, stream>>>(x2, ln2s, ln2b, h2);
  gemm32<2><<<dim3(64, 32), 256, 0, stream>>>(h2, w1T, b1, nullptr, gbuf, nullptr, nullptr,
                                              4096, 2048, 512);
  // ffn2: out = gbuf @ W2^T + b2 + x2   (direct, no split-K, no final_comb)
  gemm32<1><<<dim3(64, 8), 256, 0, stream>>>(gbuf, w2T, b2, x2, out, nullptr, nullptr,
                                             4096, 512, 2048);
}

// Round 12
// 133.009 us; speedup vs baseline: 1.1334x; 1.0541x over previous
//
#include <hip/hip_runtime.h>
#include <hip/hip_bf16.h>
#include <stdint.h>

typedef __bf16 bf16;
typedef __bf16 bf16x4 __attribute__((ext_vector_type(4)));
typedef __bf16 bf16x8 __attribute__((ext_vector_type(8)));
typedef float  f32x4  __attribute__((ext_vector_type(4)));
typedef float  f32x16 __attribute__((ext_vector_type(16)));

#define MFMA32(A_, B_, C_) __builtin_amdgcn_mfma_f32_32x32x16_bf16((A_), (B_), (C_), 0, 0, 0)

#define QSCALE 0.1803368801111137f  // 0.125 * log2(e), folded into Wq/bq

__device__ __forceinline__ void gload_lds16(const void* g, void* l) {
  __builtin_amdgcn_global_load_lds(
      (const __attribute__((address_space(1))) unsigned int*)g,
      (__attribute__((address_space(3))) unsigned int*)l, 16, 0, 0);
}

__device__ __forceinline__ unsigned pk2(float lo, float hi_) {
  union { bf16 h[2]; unsigned u; } t;
  t.h[0] = (bf16)lo; t.h[1] = (bf16)hi_;
  return t.u;
}

__device__ __forceinline__ float fast_exp2(float x) {
#if __has_builtin(__builtin_amdgcn_exp2f)
  return __builtin_amdgcn_exp2f(x);
#else
  return exp2f(x);
#endif
}

// ---------------------------------------------------------------------------
// prep_ln: blocks 0..773 = weight transposes + bias pack; 774..1797 = LN1.
// ---------------------------------------------------------------------------
__global__ __launch_bounds__(256) void prep_ln(const float* __restrict__ Wq,
                                               const float* __restrict__ Wk,
                                               const float* __restrict__ Wv,
                                               const float* __restrict__ Wo,
                                               const float* __restrict__ W1,
                                               const float* __restrict__ W2,
                                               const float* __restrict__ bq,
                                               const float* __restrict__ bk,
                                               const float* __restrict__ bv,
                                               bf16* __restrict__ wqkvT, bf16* __restrict__ woT,
                                               bf16* __restrict__ w1T, bf16* __restrict__ w2T,
                                               float* __restrict__ bqkv,
                                               const float* __restrict__ x,
                                               const float* __restrict__ ln1s,
                                               const float* __restrict__ ln1b,
                                               bf16* __restrict__ h) {
  const int b = blockIdx.x;
  if (b >= 774) {  // ---- LayerNorm rows ----
    const int w = threadIdx.x >> 6, l = threadIdx.x & 63;
    const int row = (b - 774) * 4 + w;
    const float4* xp = (const float4*)(x + (size_t)row * 512 + l * 8);
    float4 v0 = xp[0], v1 = xp[1];
    float xv[8] = {v0.x, v0.y, v0.z, v0.w, v1.x, v1.y, v1.z, v1.w};
    float s = 0.f, q = 0.f;
#pragma unroll
    for (int j = 0; j < 8; ++j) { s += xv[j]; q += xv[j] * xv[j]; }
#pragma unroll
    for (int m = 1; m < 64; m <<= 1) { s += __shfl_xor(s, m); q += __shfl_xor(q, m); }
    const float mean = s * (1.f / 512.f);
    const float var = q * (1.f / 512.f) - mean * mean;
    const float rstd = rsqrtf(var + 1e-6f);
    const float4* scp = (const float4*)(ln1s + l * 8);
    const float4* bip = (const float4*)(ln1b + l * 8);
    float4 s0 = scp[0], s1 = scp[1], b0 = bip[0], b1 = bip[1];
    float sv[8] = {s0.x, s0.y, s0.z, s0.w, s1.x, s1.y, s1.z, s1.w};
    float bvv[8] = {b0.x, b0.y, b0.z, b0.w, b1.x, b1.y, b1.z, b1.w};
    bf16x8 ov;
#pragma unroll
    for (int j = 0; j < 8; ++j) ov[j] = (bf16)((xv[j] - mean) * rstd * sv[j] + bvv[j]);
    *(bf16x8*)(h + (size_t)row * 512 + l * 8) = ov;
    return;
  }
  if (b >= 768) {  // ---- bias pack ----
    int i = (b - 768) * 256 + threadIdx.x;
    if (i < 1536)
      bqkv[i] = (i < 512) ? bq[i] * QSCALE : (i < 1024 ? bk[i - 512] : bv[i - 1024]);
    return;
  }
  const float* in; bf16* outp; int K, N, t; float sc = 1.f;
  if (b < 64)       { in = Wq; outp = wqkvT;              K = 512;  N = 512;  t = b;       sc = QSCALE; }
  else if (b < 128) { in = Wk; outp = wqkvT + 512 * 512;  K = 512;  N = 512;  t = b - 64;  }
  else if (b < 192) { in = Wv; outp = wqkvT + 1024 * 512; K = 512;  N = 512;  t = b - 128; }
  else if (b < 256) { in = Wo; outp = woT;                K = 512;  N = 512;  t = b - 192; }
  else if (b < 512) { in = W1; outp = w1T;                K = 512;  N = 2048; t = b - 256; }
  else              { in = W2; outp = w2T;                K = 2048; N = 512;  t = b - 512; }
  const int tx = K >> 6;
  const int k0 = (t % tx) * 64, n0 = (t / tx) * 64;
  __shared__ bf16 tile[64][72];
  const int tid = threadIdx.x;
#pragma unroll
  for (int s = 0; s < 16; ++s) {
    int j = tid + s * 256;
    int r = j >> 6, c = j & 63;
    tile[r][c] = (bf16)(in[(size_t)(k0 + r) * N + n0 + c] * sc);
  }
  __syncthreads();
#pragma unroll
  for (int s = 0; s < 16; ++s) {
    int j = tid + s * 256;
    int n = j >> 6, k = j & 63;
    outp[(size_t)(n0 + n) * K + k0 + k] = tile[k][n];
  }
}

// ---------------------------------------------------------------------------
// ln_k: pure LayerNorm, x2 fp32 [4096][512] -> h2 bf16. One wave per row.
// ---------------------------------------------------------------------------
__global__ __launch_bounds__(256) void ln_k(const float* __restrict__ x,
                                            const float* __restrict__ sc,
                                            const float* __restrict__ bi,
                                            bf16* __restrict__ out) {
  const int w = threadIdx.x >> 6, l = threadIdx.x & 63;
  const int row = blockIdx.x * 4 + w;
  const float4* xp = (const float4*)(x + (size_t)row * 512 + l * 8);
  float4 v0 = xp[0], v1 = xp[1];
  float xv[8] = {v0.x, v0.y, v0.z, v0.w, v1.x, v1.y, v1.z, v1.w};
  float s = 0.f, q = 0.f;
#pragma unroll
  for (int j = 0; j < 8; ++j) { s += xv[j]; q += xv[j] * xv[j]; }
#pragma unroll
  for (int m = 1; m < 64; m <<= 1) { s += __shfl_xor(s, m); q += __shfl_xor(q, m); }
  const float mean = s * (1.f / 512.f);
  const float var = q * (1.f / 512.f) - mean * mean;
  const float rstd = rsqrtf(var + 1e-6f);
  const float4* scp = (const float4*)(sc + l * 8);
  const float4* bip = (const float4*)(bi + l * 8);
  float4 s0 = scp[0], s1 = scp[1], b0 = bip[0], b1 = bip[1];
  float sv[8] = {s0.x, s0.y, s0.z, s0.w, s1.x, s1.y, s1.z, s1.w};
  float bvv[8] = {b0.x, b0.y, b0.z, b0.w, b1.x, b1.y, b1.z, b1.w};
  bf16x8 ov;
#pragma unroll
  for (int j = 0; j < 8; ++j) ov[j] = (bf16)((xv[j] - mean) * rstd * sv[j] + bvv[j]);
  *(bf16x8*)(out + (size_t)row * 512 + l * 8) = ov;
}

// ---------------------------------------------------------------------------
// GEMM32 (kept for N=512 shapes): 64x64 tile, 4 waves, 1 acc/wave, BK=64,
// 3-buffer counted-vmcnt pipeline. EPI 1: +bias+res(f32)->f32
// ---------------------------------------------------------------------------
template <int EPI>
__global__ __launch_bounds__(256, 3) void gemm32(const bf16* __restrict__ A,
                                                 const bf16* __restrict__ Bt,
                                                 const float* __restrict__ bias,
                                                 const float* __restrict__ res,
                                                 void* __restrict__ outp,
                                                 int M, int N, int K) {
  __shared__ bf16 a_lds[3][64 * 64];
  __shared__ bf16 b_lds[3][64 * 64];
  const int m0 = blockIdx.x * 64, n0 = blockIdx.y * 64;
  const int tid = threadIdx.x, l = tid & 63, w = tid >> 6;
  const int wm = w >> 1, wn = w & 1;
  const int hi = l >> 5, l5 = l & 31;
  const int lr = l >> 3;
  const int cs = (l & 7) ^ (lr & 7);
  const int swl = l5 & 7;

  const bf16* ag = A + (size_t)(m0 + w * 16 + lr) * K + cs * 8;
  const bf16* bg = Bt + (size_t)(n0 + w * 16 + lr) * K + cs * 8;
  const size_t r8 = (size_t)8 * K;

#define GS32(B_)                                                   \
  do {                                                             \
    gload_lds16(ag,      (char*)a_lds[(B_)] + (w * 16) * 128);     \
    gload_lds16(ag + r8, (char*)a_lds[(B_)] + (w * 16 + 8) * 128); \
    gload_lds16(bg,      (char*)b_lds[(B_)] + (w * 16) * 128);     \
    gload_lds16(bg + r8, (char*)b_lds[(B_)] + (w * 16 + 8) * 128); \
    ag += 64; bg += 64;                                            \
  } while (0)

  f32x16 acc = {};
  const int kiters = K >> 6;
  GS32(0);
  GS32(1);
  asm volatile("s_waitcnt vmcnt(4)" ::: "memory");
  __builtin_amdgcn_s_barrier();
  for (int kt = 0; kt < kiters; ++kt) {
    if (kt + 2 < kiters) GS32((kt + 2) % 3);
    const bf16* ab = a_lds[kt % 3] + (wm * 32 + l5) * 64;
    const bf16* bb = b_lds[kt % 3] + (wn * 32 + l5) * 64;
#pragma unroll
    for (int kk = 0; kk < 4; ++kk) {
      bf16x8 af = *(const bf16x8*)(ab + ((kk * 2 + hi) ^ swl) * 8);
      bf16x8 bf_ = *(const bf16x8*)(bb + ((kk * 2 + hi) ^ swl) * 8);
      acc = MFMA32(bf_, af, acc);
    }
    if (kt + 1 < kiters) {
      if (kt + 2 < kiters) asm volatile("s_waitcnt vmcnt(4)" ::: "memory");
      else                 asm volatile("s_waitcnt vmcnt(0)" ::: "memory");
      __builtin_amdgcn_s_barrier();
    }
  }
#undef GS32

  const int row = m0 + wm * 32 + l5;
#pragma unroll
  for (int rg = 0; rg < 4; ++rg) {
    const int cb = n0 + wn * 32 + rg * 8 + hi * 4;
    float4 bb4 = *(const float4*)(bias + cb);
    float v[4];
    v[0] = acc[rg * 4 + 0] + bb4.x;
    v[1] = acc[rg * 4 + 1] + bb4.y;
    v[2] = acc[rg * 4 + 2] + bb4.z;
    v[3] = acc[rg * 4 + 3] + bb4.w;
    float4 rr = *(const float4*)(res + (size_t)row * N + cb);
    *(float4*)((float*)outp + (size_t)row * N + cb) =
        make_float4(v[0] + rr.x, v[1] + rr.y, v[2] + rr.z, v[3] + rr.w);
  }
}

// ---------------------------------------------------------------------------
// GEMM_W: 128x128 block, 4 waves (2x2), 64x64 per wave (4x f32x16 acc),
// BK=32, 3-buffer counted-vmcnt pipeline. Each fragment feeds 2 MFMAs ->
// half the LDS-read bytes per FLOP of gemm32 (LDS-BW-bound fix).
// LDS tile layout: 64 rows x 128B; row r holds chunks lc = half*4+kc for
// A rows half*64+r, k-chunk kc; phys chunk = lc ^ (r&7) (proven swizzle).
// EPI 2: +bias,gelu->bf16   EPI 3: qkv split-write q2/k2/v2 via LDS transpose
// ---------------------------------------------------------------------------
template <int EPI>
__global__ __launch_bounds__(256, 3) void gemm_w(const bf16* __restrict__ A,
                                                 const bf16* __restrict__ Bt,
                                                 const float* __restrict__ bias,
                                                 void* __restrict__ outp,
                                                 bf16* __restrict__ k2,
                                                 bf16* __restrict__ v2,
                                                 int M, int N, int K) {
  __shared__ __align__(16) char smem[49152];
  char* a_lds = smem;           // [3][8192]
  char* b_lds = smem + 24576;   // [3][8192]
  const int tid = threadIdx.x, l = tid & 63, w = tid >> 6;
  const int wm = w >> 1, wn = w & 1;
  const int hi = l >> 5, l5 = l & 31;
  const int m0 = blockIdx.x * 128, n0 = blockIdx.y * 128;
  const int swl = l5 & 7;

  // staging mapping: slot s=tid covers LDS row sr=tid>>3, phys chunk sp=tid&7
  const int sr = tid >> 3, sp = tid & 7;
  const int slc = sp ^ (sr & 7);            // logical chunk
  const int shalf = slc >> 2, skc = slc & 3;
  const bf16* ag = A + (size_t)(m0 + shalf * 64 + sr) * K + skc * 8;
  const bf16* bg = Bt + (size_t)(n0 + shalf * 64 + sr) * K + skc * 8;
  const size_t r32 = (size_t)32 * K;        // slot tid+256: row sr+32, same chunk

#define GSW(B_)                                                       \
  do {                                                                \
    gload_lds16(ag,       a_lds + (B_) * 8192 + w * 1024);            \
    gload_lds16(ag + r32, a_lds + (B_) * 8192 + 4096 + w * 1024);     \
    gload_lds16(bg,       b_lds + (B_) * 8192 + w * 1024);            \
    gload_lds16(bg + r32, b_lds + (B_) * 8192 + 4096 + w * 1024);     \
    ag += 32; bg += 32;                                               \
  } while (0)

  f32x16 acc00 = {}, acc01 = {}, acc10 = {}, acc11 = {};
  const int kiters = K >> 5;
  GSW(0);
  GSW(1);
  asm volatile("s_waitcnt vmcnt(4)" ::: "memory");
  __builtin_amdgcn_s_barrier();
  for (int kt = 0; kt < kiters; ++kt) {
    if (kt + 2 < kiters) GSW((kt + 2) % 3);
    const char* ab = a_lds + (kt % 3) * 8192;
    const char* bb = b_lds + (kt % 3) * 8192;
#pragma unroll
    for (int kk = 0; kk < 2; ++kk) {
      bf16x8 af0 = *(const bf16x8*)(ab + (l5)*128      + ((wm * 4 + kk * 2 + hi) ^ swl) * 16);
      bf16x8 af1 = *(const bf16x8*)(ab + (32 + l5)*128 + ((wm * 4 + kk * 2 + hi) ^ swl) * 16);
      bf16x8 bf0 = *(const bf16x8*)(bb + (l5)*128      + ((wn * 4 + kk * 2 + hi) ^ swl) * 16);
      bf16x8 bf1 = *(const bf16x8*)(bb + (32 + l5)*128 + ((wn * 4 + kk * 2 + hi) ^ swl) * 16);
      acc00 = MFMA32(bf0, af0, acc00);
      acc01 = MFMA32(bf1, af0, acc01);
      acc10 = MFMA32(bf0, af1, acc10);
      acc11 = MFMA32(bf1, af1, acc11);
    }
    if (kt + 1 < kiters) {
      if (kt + 2 < kiters) asm volatile("s_waitcnt vmcnt(4)" ::: "memory");
      else                 asm volatile("s_waitcnt vmcnt(0)" ::: "memory");
      __builtin_amdgcn_s_barrier();
    }
  }
#undef GSW

  if constexpr (EPI == 2) {  // gelu -> bf16, direct stores
#pragma unroll
    for (int mi = 0; mi < 2; ++mi) {
      const int row = m0 + wm * 64 + mi * 32 + l5;
#pragma unroll
      for (int ni = 0; ni < 2; ++ni) {
        const f32x16& ac = (mi == 0) ? (ni == 0 ? acc00 : acc01)
                                     : (ni == 0 ? acc10 : acc11);
#pragma unroll
        for (int rg = 0; rg < 4; ++rg) {
          const int cb = n0 + wn * 64 + ni * 32 + rg * 8 + hi * 4;
          float4 bb4 = *(const float4*)(bias + cb);
          float v[4] = {ac[rg * 4 + 0] + bb4.x, ac[rg * 4 + 1] + bb4.y,
                        ac[rg * 4 + 2] + bb4.z, ac[rg * 4 + 3] + bb4.w};
          bf16x4 o;
#pragma unroll
          for (int e = 0; e < 4; ++e) {
            float t = -2.3022077697f * (v[e] + 0.044715f * v[e] * v[e] * v[e]);
            o[e] = (bf16)(v[e] / (1.f + fast_exp2(t)));
          }
          *(bf16x4*)((bf16*)outp + (size_t)row * N + cb) = o;
        }
      }
    }
  } else {  // EPI 3: C tile -> LDS (padded) -> coalesced q2/k2/v2
    __syncthreads();                       // all waves done reading tiles
    bf16(*ct)[136] = (bf16(*)[136])smem;   // 128 x 136 bf16 = 34816 B
#pragma unroll
    for (int mi = 0; mi < 2; ++mi) {
      const int rl = wm * 64 + mi * 32 + l5;
#pragma unroll
      for (int ni = 0; ni < 2; ++ni) {
        const f32x16& ac = (mi == 0) ? (ni == 0 ? acc00 : acc01)
                                     : (ni == 0 ? acc10 : acc11);
#pragma unroll
        for (int rg = 0; rg < 4; ++rg) {
          const int cl = wn * 64 + ni * 32 + rg * 8 + hi * 4;
          float4 bb4 = *(const float4*)(bias + n0 + cl);
          bf16x4 o;
          o[0] = (bf16)(ac[rg * 4 + 0] + bb4.x);
          o[1] = (bf16)(ac[rg * 4 + 1] + bb4.y);
          o[2] = (bf16)(ac[rg * 4 + 2] + bb4.z);
          o[3] = (bf16)(ac[rg * 4 + 3] + bb4.w);
          *(bf16x4*)(&ct[rl][cl]) = o;
        }
      }
    }
    __syncthreads();
    if (n0 < 512) {            // q2 [t][512]
#pragma unroll
      for (int p = 0; p < 8; ++p) {
        int v = p * 256 + tid;
        int r = v >> 4, c8 = (v & 15) * 8;
        *(bf16x8*)((bf16*)outp + (size_t)(m0 + r) * 512 + n0 + c8) =
            *(const bf16x8*)(&ct[r][c8]);
      }
    } else if (n0 < 1024) {    // k2 [h][t][64], 2 heads per 128-col tile
      const int hb = (n0 - 512) >> 6;
#pragma unroll
      for (int p = 0; p < 8; ++p) {
        int v = p * 256 + tid;
        int r = v >> 4, c8 = (v & 15) * 8;
        *(bf16x8*)(k2 + (size_t)(hb + (c8 >> 6)) * 262144 +
                   (size_t)(m0 + r) * 64 + (c8 & 63)) = *(const bf16x8*)(&ct[r][c8]);
      }
    } else {                   // v2 [h][panel][d][32], 2 heads, 4 panels
      const int hb = (n0 - 1024) >> 6;
      const int d = tid >> 2, t8 = (tid & 3) * 8;
#pragma unroll
      for (int h2 = 0; h2 < 2; ++h2) {
        bf16* vb = v2 + (size_t)(hb + h2) * 262144 + (size_t)(m0 >> 5) * 2048;
#pragma unroll
        for (int p = 0; p < 4; ++p) {
          bf16x8 vv;
#pragma unroll
          for (int e = 0; e < 8; ++e) vv[e] = ct[p * 32 + t8 + e][h2 * 64 + d];
          *(bf16x8*)(vb + p * 2048 + d * 32 + t8) = vv;
        }
      }
    }
  }
}

// ---------------------------------------------------------------------------
// Flash attention v8 (frozen at measured 52us): 8 waves/block, grid 512 =
// qt(64) x head(8). LDS dbuf staging from dense k2/v2, one barrier/tile,
// constant-max in-register softmax, raw v_exp2, permlane pack.
// ---------------------------------------------------------------------------
__global__ __launch_bounds__(512, 4) void attn_k(const bf16* __restrict__ q2,
                                                 const bf16* __restrict__ k2,
                                                 const bf16* __restrict__ v2,
                                                 bf16* __restrict__ attnb) {
  const int bid = blockIdx.x;
  const int head = bid & 7;          // one head per XCD (L2 locality)
  const int qt = bid >> 3;
  const int w = threadIdx.x >> 6, l = threadIdx.x & 63;
  const int hi = l >> 5, l5 = l & 31;
  const int pair = w >> 1, wq = w & 1;

  __shared__ __align__(16) char smem[65536];
  char* kt_l = smem + pair * 16384;   // [2][4096] B
  char* vt_l = kt_l + 8192;           // [2][4096] B

  const int qrow0 = qt * 64 + wq * 32;
  const bf16* qb = q2 + (size_t)(qrow0 + l5) * 512 + head * 64;
  bf16x8 qf[4];
#pragma unroll
  for (int cc = 0; cc < 4; ++cc) qf[cc] = *(const bf16x8*)(qb + cc * 16 + hi * 8);

  const int kstart = pair * 1024;

  const int lr = l >> 3;
  const int lc3 = (l & 7) ^ lr;
  const char* kg = (const char*)k2 + (size_t)head * 524288 + (size_t)kstart * 128 +
                   (wq * 16 + lr) * 128 + lc3 * 16;
  const char* vg = (const char*)v2 + (size_t)head * 524288 + (size_t)(kstart >> 5) * 4096 +
                   (lc3 >> 2) * 2048 + (wq * 16 + lr) * 64 + (lc3 & 3) * 16;
  const int kdst = wq * 2048;

#define STAGE(B_)                                                            \
  do {                                                                       \
    gload_lds16(kg,        kt_l + (B_) * 4096 + kdst);                       \
    gload_lds16(kg + 1024, kt_l + (B_) * 4096 + kdst + 1024);                \
    gload_lds16(vg,        vt_l + (B_) * 4096 + kdst);                       \
    gload_lds16(vg + 512,  vt_l + (B_) * 4096 + kdst + 1024);                \
    kg += 4096; vg += 4096;                                                  \
  } while (0)

  STAGE(0);
  __syncthreads();

  f32x16 o0 = {}, o1 = {};
  float psum = 0.f;
  const int swl = l5 & 7;
  const char* kbase = kt_l + l5 * 128;
  const char* vbase = vt_l + l5 * 128;

  for (int t = 0; t < 32; ++t) {
    const int cur = t & 1;
    if (t < 31) STAGE(cur ^ 1);

    __builtin_amdgcn_s_setprio(1);
    f32x16 s = {};
#pragma unroll
    for (int cc = 0; cc < 4; ++cc) {
      bf16x8 kf = *(const bf16x8*)(kbase + cur * 4096 + ((cc * 2 + hi) ^ swl) * 16);
      s = MFMA32(kf, qf[cc], s);
    }
    __builtin_amdgcn_s_setprio(0);

#pragma unroll
    for (int c = 0; c < 2; ++c) {
      float p[8];
#pragma unroll
      for (int j = 0; j < 8; ++j) p[j] = fast_exp2(s[c * 8 + j]);
      psum += ((p[0] + p[1]) + (p[2] + p[3])) + ((p[4] + p[5]) + (p[6] + p[7]));
      unsigned X = pk2(p[0], p[1]), X2 = pk2(p[2], p[3]);
      unsigned Y = pk2(p[4], p[5]), Y2 = pk2(p[6], p[7]);
      asm volatile("v_permlane32_swap_b32 %0, %1" : "+v"(X), "+v"(Y));
      asm volatile("v_permlane32_swap_b32 %0, %1" : "+v"(X2), "+v"(Y2));
      union { unsigned wd[4]; bf16x8 v; } pa;
      pa.wd[0] = X; pa.wd[1] = X2; pa.wd[2] = Y; pa.wd[3] = Y2;
      bf16x8 vf0 = *(const bf16x8*)(vbase + cur * 4096 + ((c * 2 + hi) ^ swl) * 16);
      bf16x8 vf1 = *(const bf16x8*)(vbase + cur * 4096 + ((4 + c * 2 + hi) ^ swl) * 16);
      __builtin_amdgcn_s_setprio(1);
      o0 = MFMA32(vf0, pa.v, o0);
      o1 = MFMA32(vf1, pa.v, o1);
      __builtin_amdgcn_s_setprio(0);
    }
    __syncthreads();
  }
#undef STAGE

  // 4-way key-range combine via LDS (tiles dead). 6 slots x 64 x 33 f32.
  float* comb = (float*)smem;
  if (pair > 0) {
    float* cb = comb + (((pair - 1) * 2 + wq) * 64 + l) * 33;
#pragma unroll
    for (int r = 0; r < 16; ++r) { cb[r] = o0[r]; cb[16 + r] = o1[r]; }
    cb[32] = psum;
  }
  __syncthreads();
  if (pair == 0) {
#pragma unroll
    for (int p = 0; p < 3; ++p) {
      const float* cb = comb + ((p * 2 + wq) * 64 + l) * 33;
#pragma unroll
      for (int r = 0; r < 16; ++r) { o0[r] += cb[r]; o1[r] += cb[16 + r]; }
      psum += cb[32];
    }
    const float lsum = psum + __shfl_xor(psum, 32);
    const float inv = 1.f / lsum;
    bf16* ob = attnb + (size_t)(qrow0 + l5) * 512 + head * 64;
#pragma unroll
    for (int dt = 0; dt < 2; ++dt)
#pragma unroll
      for (int rg = 0; rg < 4; ++rg) {
        bf16x4 vv;
#pragma unroll
        for (int e = 0; e < 4; ++e) {
          const float ov = (dt == 0) ? o0[rg * 4 + e] : o1[rg * 4 + e];
          vv[e] = (bf16)(ov * inv);
        }
        *(bf16x4*)(ob + dt * 32 + rg * 8 + hi * 4) = vv;
      }
  }
}

// ---------------------------------------------------------------------------
extern "C" void kernel_launch(void* const* d_in, const int* in_sizes, int n_in,
                              void* d_out, int out_size, void* d_ws, size_t ws_size,
                              hipStream_t stream) {
  const float* x    = (const float*)d_in[0];
  const float* ln1s = (const float*)d_in[1];
  const float* ln1b = (const float*)d_in[2];
  const float* Wq   = (const float*)d_in[3];
  const float* bq   = (const float*)d_in[4];
  const float* Wk   = (const float*)d_in[5];
  const float* bk   = (const float*)d_in[6];
  const float* Wv   = (const float*)d_in[7];
  const float* bv   = (const float*)d_in[8];
  const float* Wo   = (const float*)d_in[9];
  const float* bo   = (const float*)d_in[10];
  const float* ln2s = (const float*)d_in[11];
  const float* ln2b = (const float*)d_in[12];
  const float* W1   = (const float*)d_in[13];
  const float* b1   = (const float*)d_in[14];
  const float* W2   = (const float*)d_in[15];
  const float* b2   = (const float*)d_in[16];
  float* out = (float*)d_out;

  char* ws = (char*)d_ws;
  bf16*  wqkvT = (bf16*)(ws + 0);          // [1536][512] 1.5M
  bf16*  woT   = (bf16*)(ws + 1572864);    // [512][512]  0.5M
  bf16*  w1T   = (bf16*)(ws + 2097152);    // [2048][512] 2M
  bf16*  w2T   = (bf16*)(ws + 4194304);    // [512][2048] 2M
  float* bqkv  = (float*)(ws + 6291456);   // -> 6297600
  float* x2    = (float*)(ws + 6297600);   // [4096][512] f32 8M -> 14686208
  bf16*  h     = (bf16*)(ws + 14686208);   // 4M -> 18880512 (h / attnb / h2)
  bf16*  q2    = (bf16*)(ws + 18880512);   // 4M -> 23074816
  bf16*  k2    = (bf16*)(ws + 23074816);   // 4M -> 27269120
  bf16*  v2    = (bf16*)(ws + 27269120);   // 4M -> 31463424
  bf16*  attnb = h;
  bf16*  h2    = h;
  bf16*  gbuf  = (bf16*)(ws + 18880512);   // ffn1 out 16M over dead q2/k2/v2

  prep_ln<<<1798, 256, 0, stream>>>(Wq, Wk, Wv, Wo, W1, W2, bq, bk, bv,
                                    wqkvT, woT, w1T, w2T, bqkv, x, ln1s, ln1b, h);
  gemm_w<3><<<dim3(32, 12), 256, 0, stream>>>(h, wqkvT, bqkv, q2, k2, v2,
                                              4096, 1536, 512);
  attn_k<<<512, 512, 0, stream>>>(q2, k2, v2, attnb);
  // wo projection: x2 = attnb @ Wo^T + bo + x
  gemm32<1><<<dim3(64, 8), 256, 0, stream>>>(attnb, woT, bo, x, x2, 4096, 512, 512);
  ln_k<<<1024, 256, 0, stream>>>(x2, ln2s, ln2b, h2);
  gemm_w<2><<<dim3(32, 16), 256, 0, stream>>>(h2, w1T, b1, gbuf, nullptr, nullptr,
                                              4096, 2048, 512);
  // ffn2: out = gbuf @ W2^T + b2 + x2
  gemm32<1><<<dim3(64, 8), 256, 0, stream>>>(gbuf, w2T, b2, x2, out, 4096, 512, 2048);
}

// Round 13
// 131.125 us; speedup vs baseline: 1.1497x; 1.0144x over previous
//
#include <hip/hip_runtime.h>
#include <hip/hip_bf16.h>
#include <stdint.h>

typedef __bf16 bf16;
typedef __bf16 bf16x4 __attribute__((ext_vector_type(4)));
typedef __bf16 bf16x8 __attribute__((ext_vector_type(8)));
typedef float  f32x4  __attribute__((ext_vector_type(4)));
typedef float  f32x16 __attribute__((ext_vector_type(16)));

#define MFMA32(A_, B_, C_) __builtin_amdgcn_mfma_f32_32x32x16_bf16((A_), (B_), (C_), 0, 0, 0)

#define QSCALE 0.1803368801111137f  // 0.125 * log2(e), folded into Wq/bq

__device__ __forceinline__ void gload_lds16(const void* g, void* l) {
  __builtin_amdgcn_global_load_lds(
      (const __attribute__((address_space(1))) unsigned int*)g,
      (__attribute__((address_space(3))) unsigned int*)l, 16, 0, 0);
}

__device__ __forceinline__ unsigned pk2(float lo, float hi_) {
  union { bf16 h[2]; unsigned u; } t;
  t.h[0] = (bf16)lo; t.h[1] = (bf16)hi_;
  return t.u;
}

__device__ __forceinline__ float fast_exp2(float x) {
#if __has_builtin(__builtin_amdgcn_exp2f)
  return __builtin_amdgcn_exp2f(x);
#else
  return exp2f(x);
#endif
}

// ---------------------------------------------------------------------------
// prep_ln: blocks 0..773 = weight transposes + bias pack; 774..1797 = LN1.
// ---------------------------------------------------------------------------
__global__ __launch_bounds__(256) void prep_ln(const float* __restrict__ Wq,
                                               const float* __restrict__ Wk,
                                               const float* __restrict__ Wv,
                                               const float* __restrict__ Wo,
                                               const float* __restrict__ W1,
                                               const float* __restrict__ W2,
                                               const float* __restrict__ bq,
                                               const float* __restrict__ bk,
                                               const float* __restrict__ bv,
                                               bf16* __restrict__ wqkvT, bf16* __restrict__ woT,
                                               bf16* __restrict__ w1T, bf16* __restrict__ w2T,
                                               float* __restrict__ bqkv,
                                               const float* __restrict__ x,
                                               const float* __restrict__ ln1s,
                                               const float* __restrict__ ln1b,
                                               bf16* __restrict__ h) {
  const int b = blockIdx.x;
  if (b >= 774) {  // ---- LayerNorm rows ----
    const int w = threadIdx.x >> 6, l = threadIdx.x & 63;
    const int row = (b - 774) * 4 + w;
    const float4* xp = (const float4*)(x + (size_t)row * 512 + l * 8);
    float4 v0 = xp[0], v1 = xp[1];
    float xv[8] = {v0.x, v0.y, v0.z, v0.w, v1.x, v1.y, v1.z, v1.w};
    float s = 0.f, q = 0.f;
#pragma unroll
    for (int j = 0; j < 8; ++j) { s += xv[j]; q += xv[j] * xv[j]; }
#pragma unroll
    for (int m = 1; m < 64; m <<= 1) { s += __shfl_xor(s, m); q += __shfl_xor(q, m); }
    const float mean = s * (1.f / 512.f);
    const float var = q * (1.f / 512.f) - mean * mean;
    const float rstd = rsqrtf(var + 1e-6f);
    const float4* scp = (const float4*)(ln1s + l * 8);
    const float4* bip = (const float4*)(ln1b + l * 8);
    float4 s0 = scp[0], s1 = scp[1], b0 = bip[0], b1 = bip[1];
    float sv[8] = {s0.x, s0.y, s0.z, s0.w, s1.x, s1.y, s1.z, s1.w};
    float bvv[8] = {b0.x, b0.y, b0.z, b0.w, b1.x, b1.y, b1.z, b1.w};
    bf16x8 ov;
#pragma unroll
    for (int j = 0; j < 8; ++j) ov[j] = (bf16)((xv[j] - mean) * rstd * sv[j] + bvv[j]);
    *(bf16x8*)(h + (size_t)row * 512 + l * 8) = ov;
    return;
  }
  if (b >= 768) {  // ---- bias pack ----
    int i = (b - 768) * 256 + threadIdx.x;
    if (i < 1536)
      bqkv[i] = (i < 512) ? bq[i] * QSCALE : (i < 1024 ? bk[i - 512] : bv[i - 1024]);
    return;
  }
  const float* in; bf16* outp; int K, N, t; float sc = 1.f;
  if (b < 64)       { in = Wq; outp = wqkvT;              K = 512;  N = 512;  t = b;       sc = QSCALE; }
  else if (b < 128) { in = Wk; outp = wqkvT + 512 * 512;  K = 512;  N = 512;  t = b - 64;  }
  else if (b < 192) { in = Wv; outp = wqkvT + 1024 * 512; K = 512;  N = 512;  t = b - 128; }
  else if (b < 256) { in = Wo; outp = woT;                K = 512;  N = 512;  t = b - 192; }
  else if (b < 512) { in = W1; outp = w1T;                K = 512;  N = 2048; t = b - 256; }
  else              { in = W2; outp = w2T;                K = 2048; N = 512;  t = b - 512; }
  const int tx = K >> 6;
  const int k0 = (t % tx) * 64, n0 = (t / tx) * 64;
  __shared__ bf16 tile[64][72];
  const int tid = threadIdx.x;
#pragma unroll
  for (int s = 0; s < 16; ++s) {
    int j = tid + s * 256;
    int r = j >> 6, c = j & 63;
    tile[r][c] = (bf16)(in[(size_t)(k0 + r) * N + n0 + c] * sc);
  }
  __syncthreads();
#pragma unroll
  for (int s = 0; s < 16; ++s) {
    int j = tid + s * 256;
    int n = j >> 6, k = j & 63;
    outp[(size_t)(n0 + n) * K + k0 + k] = tile[k][n];
  }
}

// ---------------------------------------------------------------------------
// ln_k: pure LayerNorm, x2 fp32 [4096][512] -> h2 bf16. One wave per row.
// ---------------------------------------------------------------------------
__global__ __launch_bounds__(256) void ln_k(const float* __restrict__ x,
                                            const float* __restrict__ sc,
                                            const float* __restrict__ bi,
                                            bf16* __restrict__ out) {
  const int w = threadIdx.x >> 6, l = threadIdx.x & 63;
  const int row = blockIdx.x * 4 + w;
  const float4* xp = (const float4*)(x + (size_t)row * 512 + l * 8);
  float4 v0 = xp[0], v1 = xp[1];
  float xv[8] = {v0.x, v0.y, v0.z, v0.w, v1.x, v1.y, v1.z, v1.w};
  float s = 0.f, q = 0.f;
#pragma unroll
  for (int j = 0; j < 8; ++j) { s += xv[j]; q += xv[j] * xv[j]; }
#pragma unroll
  for (int m = 1; m < 64; m <<= 1) { s += __shfl_xor(s, m); q += __shfl_xor(q, m); }
  const float mean = s * (1.f / 512.f);
  const float var = q * (1.f / 512.f) - mean * mean;
  const float rstd = rsqrtf(var + 1e-6f);
  const float4* scp = (const float4*)(sc + l * 8);
  const float4* bip = (const float4*)(bi + l * 8);
  float4 s0 = scp[0], s1 = scp[1], b0 = bip[0], b1 = bip[1];
  float sv[8] = {s0.x, s0.y, s0.z, s0.w, s1.x, s1.y, s1.z, s1.w};
  float bvv[8] = {b0.x, b0.y, b0.z, b0.w, b1.x, b1.y, b1.z, b1.w};
  bf16x8 ov;
#pragma unroll
  for (int j = 0; j < 8; ++j) ov[j] = (bf16)((xv[j] - mean) * rstd * sv[j] + bvv[j]);
  *(bf16x8*)(out + (size_t)row * 512 + l * 8) = ov;
}

// ---------------------------------------------------------------------------
// GEMM_N64 (for N=512 outputs): 128x64 tile, 4 waves (2Mx2N, 64x32/wave,
// 2 acc), BK=32, 3-buffer counted-vmcnt pipeline (3 loads/stage ->
// vmcnt(3) steady). Reads/MFMA = 1.5 (af0/af1 reused via shared bf).
// LDS: A [64r][128B] (2 row-halves), B [32r][128B] (2 col-halves), ^(r&7).
// EPI 1: +bias+res(f32)->f32
// ---------------------------------------------------------------------------
template <int EPI>
__global__ __launch_bounds__(256, 4) void gemm_n64(const bf16* __restrict__ A,
                                                   const bf16* __restrict__ Bt,
                                                   const float* __restrict__ bias,
                                                   const float* __restrict__ res,
                                                   void* __restrict__ outp,
                                                   int M, int N, int K) {
  __shared__ __align__(16) char smem[36864];   // 3 x (8192 A + 4096 B)
  const int tid = threadIdx.x, l = tid & 63, w = tid >> 6;
  const int wm = w >> 1, wn = w & 1;
  const int hi = l >> 5, l5 = l & 31;
  const int m0 = blockIdx.x * 128, n0 = blockIdx.y * 64;
  const int swl = l5 & 7;

  // A staging: slot tid -> LDS row tid>>3, phys chunk tid&7 (and +32 rows)
  const int sr = tid >> 3, sp = tid & 7;
  const int slc = sp ^ (sr & 7);
  const int shalf = slc >> 2, skc = slc & 3;
  const bf16* ag = A + (size_t)(m0 + shalf * 64 + sr) * K + skc * 8;
  const size_t r32 = (size_t)32 * K;
  // B staging: slot tid covers 32 rows x 8 chunks
  const int brow = tid >> 3;   // same as sr but semantically B row within 32
  const int blc = sp ^ (brow & 7);
  const bf16* bg = Bt + (size_t)(n0 + (blc >> 2) * 32 + brow) * K + (blc & 3) * 8;

#define GSN(B_)                                                          \
  do {                                                                   \
    char* ab_ = smem + (B_) * 12288;                                     \
    gload_lds16(ag,       ab_ + w * 1024);                               \
    gload_lds16(ag + r32, ab_ + 4096 + w * 1024);                        \
    gload_lds16(bg,       ab_ + 8192 + w * 1024);                        \
    ag += 32; bg += 32;                                                  \
  } while (0)

  f32x16 acc0 = {}, acc1 = {};
  const int kiters = K >> 5;
  GSN(0);
  GSN(1);
  asm volatile("s_waitcnt vmcnt(3)" ::: "memory");
  __builtin_amdgcn_s_barrier();
  for (int kt = 0; kt < kiters; ++kt) {
    if (kt + 2 < kiters) GSN((kt + 2) % 3);
    const char* ab = smem + (kt % 3) * 12288;
    const char* bb = ab + 8192;
#pragma unroll
    for (int kk = 0; kk < 2; ++kk) {
      bf16x8 af0 = *(const bf16x8*)(ab + (l5)*128      + ((wm * 4 + kk * 2 + hi) ^ swl) * 16);
      bf16x8 af1 = *(const bf16x8*)(ab + (32 + l5)*128 + ((wm * 4 + kk * 2 + hi) ^ swl) * 16);
      bf16x8 bf_ = *(const bf16x8*)(bb + (l5)*128      + ((wn * 4 + kk * 2 + hi) ^ swl) * 16);
      acc0 = MFMA32(bf_, af0, acc0);
      acc1 = MFMA32(bf_, af1, acc1);
    }
    if (kt + 1 < kiters) {
      if (kt + 2 < kiters) asm volatile("s_waitcnt vmcnt(3)" ::: "memory");
      else                 asm volatile("s_waitcnt vmcnt(0)" ::: "memory");
      __builtin_amdgcn_s_barrier();
    }
  }
#undef GSN

#pragma unroll
  for (int mi = 0; mi < 2; ++mi) {
    const int row = m0 + wm * 64 + mi * 32 + l5;
    const f32x16& ac = (mi == 0) ? acc0 : acc1;
#pragma unroll
    for (int rg = 0; rg < 4; ++rg) {
      const int cb = n0 + wn * 32 + rg * 8 + hi * 4;
      float4 bb4 = *(const float4*)(bias + cb);
      float4 rr = *(const float4*)(res + (size_t)row * N + cb);
      *(float4*)((float*)outp + (size_t)row * N + cb) =
          make_float4(ac[rg * 4 + 0] + bb4.x + rr.x, ac[rg * 4 + 1] + bb4.y + rr.y,
                      ac[rg * 4 + 2] + bb4.z + rr.z, ac[rg * 4 + 3] + bb4.w + rr.w);
    }
  }
}

// ---------------------------------------------------------------------------
// GEMM_W: 128x128 block, 4 waves (2x2), 64x64 per wave (4x f32x16 acc),
// BK=32, 3-buffer counted-vmcnt pipeline. Fragment reuse 2.
// EPI 2: +bias,gelu->bf16   EPI 3: qkv split-write q2/k2/v2 via LDS transpose
// ---------------------------------------------------------------------------
template <int EPI>
__global__ __launch_bounds__(256, 3) void gemm_w(const bf16* __restrict__ A,
                                                 const bf16* __restrict__ Bt,
                                                 const float* __restrict__ bias,
                                                 void* __restrict__ outp,
                                                 bf16* __restrict__ k2,
                                                 bf16* __restrict__ v2,
                                                 int M, int N, int K) {
  __shared__ __align__(16) char smem[49152];
  char* a_lds = smem;           // [3][8192]
  char* b_lds = smem + 24576;   // [3][8192]
  const int tid = threadIdx.x, l = tid & 63, w = tid >> 6;
  const int wm = w >> 1, wn = w & 1;
  const int hi = l >> 5, l5 = l & 31;
  const int m0 = blockIdx.x * 128, n0 = blockIdx.y * 128;
  const int swl = l5 & 7;

  const int sr = tid >> 3, sp = tid & 7;
  const int slc = sp ^ (sr & 7);
  const int shalf = slc >> 2, skc = slc & 3;
  const bf16* ag = A + (size_t)(m0 + shalf * 64 + sr) * K + skc * 8;
  const bf16* bg = Bt + (size_t)(n0 + shalf * 64 + sr) * K + skc * 8;
  const size_t r32 = (size_t)32 * K;

#define GSW(B_)                                                       \
  do {                                                                \
    gload_lds16(ag,       a_lds + (B_) * 8192 + w * 1024);            \
    gload_lds16(ag + r32, a_lds + (B_) * 8192 + 4096 + w * 1024);     \
    gload_lds16(bg,       b_lds + (B_) * 8192 + w * 1024);            \
    gload_lds16(bg + r32, b_lds + (B_) * 8192 + 4096 + w * 1024);     \
    ag += 32; bg += 32;                                               \
  } while (0)

  f32x16 acc00 = {}, acc01 = {}, acc10 = {}, acc11 = {};
  const int kiters = K >> 5;
  GSW(0);
  GSW(1);
  asm volatile("s_waitcnt vmcnt(4)" ::: "memory");
  __builtin_amdgcn_s_barrier();
  for (int kt = 0; kt < kiters; ++kt) {
    if (kt + 2 < kiters) GSW((kt + 2) % 3);
    const char* ab = a_lds + (kt % 3) * 8192;
    const char* bb = b_lds + (kt % 3) * 8192;
#pragma unroll
    for (int kk = 0; kk < 2; ++kk) {
      bf16x8 af0 = *(const bf16x8*)(ab + (l5)*128      + ((wm * 4 + kk * 2 + hi) ^ swl) * 16);
      bf16x8 af1 = *(const bf16x8*)(ab + (32 + l5)*128 + ((wm * 4 + kk * 2 + hi) ^ swl) * 16);
      bf16x8 bf0 = *(const bf16x8*)(bb + (l5)*128      + ((wn * 4 + kk * 2 + hi) ^ swl) * 16);
      bf16x8 bf1 = *(const bf16x8*)(bb + (32 + l5)*128 + ((wn * 4 + kk * 2 + hi) ^ swl) * 16);
      acc00 = MFMA32(bf0, af0, acc00);
      acc01 = MFMA32(bf1, af0, acc01);
      acc10 = MFMA32(bf0, af1, acc10);
      acc11 = MFMA32(bf1, af1, acc11);
    }
    if (kt + 1 < kiters) {
      if (kt + 2 < kiters) asm volatile("s_waitcnt vmcnt(4)" ::: "memory");
      else                 asm volatile("s_waitcnt vmcnt(0)" ::: "memory");
      __builtin_amdgcn_s_barrier();
    }
  }
#undef GSW

  if constexpr (EPI == 2) {  // gelu -> bf16, direct stores
#pragma unroll
    for (int mi = 0; mi < 2; ++mi) {
      const int row = m0 + wm * 64 + mi * 32 + l5;
#pragma unroll
      for (int ni = 0; ni < 2; ++ni) {
        const f32x16& ac = (mi == 0) ? (ni == 0 ? acc00 : acc01)
                                     : (ni == 0 ? acc10 : acc11);
#pragma unroll
        for (int rg = 0; rg < 4; ++rg) {
          const int cb = n0 + wn * 64 + ni * 32 + rg * 8 + hi * 4;
          float4 bb4 = *(const float4*)(bias + cb);
          float v[4] = {ac[rg * 4 + 0] + bb4.x, ac[rg * 4 + 1] + bb4.y,
                        ac[rg * 4 + 2] + bb4.z, ac[rg * 4 + 3] + bb4.w};
          bf16x4 o;
#pragma unroll
          for (int e = 0; e < 4; ++e) {
            float t = -2.3022077697f * (v[e] + 0.044715f * v[e] * v[e] * v[e]);
            o[e] = (bf16)(v[e] / (1.f + fast_exp2(t)));
          }
          *(bf16x4*)((bf16*)outp + (size_t)row * N + cb) = o;
        }
      }
    }
  } else {  // EPI 3: C tile -> LDS (padded) -> coalesced q2/k2/v2
    __syncthreads();
    bf16(*ct)[136] = (bf16(*)[136])smem;   // 128 x 136 bf16
#pragma unroll
    for (int mi = 0; mi < 2; ++mi) {
      const int rl = wm * 64 + mi * 32 + l5;
#pragma unroll
      for (int ni = 0; ni < 2; ++ni) {
        const f32x16& ac = (mi == 0) ? (ni == 0 ? acc00 : acc01)
                                     : (ni == 0 ? acc10 : acc11);
#pragma unroll
        for (int rg = 0; rg < 4; ++rg) {
          const int cl = wn * 64 + ni * 32 + rg * 8 + hi * 4;
          float4 bb4 = *(const float4*)(bias + n0 + cl);
          bf16x4 o;
          o[0] = (bf16)(ac[rg * 4 + 0] + bb4.x);
          o[1] = (bf16)(ac[rg * 4 + 1] + bb4.y);
          o[2] = (bf16)(ac[rg * 4 + 2] + bb4.z);
          o[3] = (bf16)(ac[rg * 4 + 3] + bb4.w);
          *(bf16x4*)(&ct[rl][cl]) = o;
        }
      }
    }
    __syncthreads();
    if (n0 < 512) {            // q2 [t][512]
#pragma unroll
      for (int p = 0; p < 8; ++p) {
        int v = p * 256 + tid;
        int r = v >> 4, c8 = (v & 15) * 8;
        *(bf16x8*)((bf16*)outp + (size_t)(m0 + r) * 512 + n0 + c8) =
            *(const bf16x8*)(&ct[r][c8]);
      }
    } else if (n0 < 1024) {    // k2 [h][t][64], 2 heads per 128-col tile
      const int hb = (n0 - 512) >> 6;
#pragma unroll
      for (int p = 0; p < 8; ++p) {
        int v = p * 256 + tid;
        int r = v >> 4, c8 = (v & 15) * 8;
        *(bf16x8*)(k2 + (size_t)(hb + (c8 >> 6)) * 262144 +
                   (size_t)(m0 + r) * 64 + (c8 & 63)) = *(const bf16x8*)(&ct[r][c8]);
      }
    } else {                   // v2 [h][panel][d][32], 2 heads, 4 panels
      const int hb = (n0 - 1024) >> 6;
      const int d = tid >> 2, t8 = (tid & 3) * 8;
#pragma unroll
      for (int h2 = 0; h2 < 2; ++h2) {
        bf16* vb = v2 + (size_t)(hb + h2) * 262144 + (size_t)(m0 >> 5) * 2048;
#pragma unroll
        for (int p = 0; p < 4; ++p) {
          bf16x8 vv;
#pragma unroll
          for (int e = 0; e < 8; ++e) vv[e] = ct[p * 32 + t8 + e][h2 * 64 + d];
          *(bf16x8*)(vb + p * 2048 + d * 32 + t8) = vv;
        }
      }
    }
  }
}

// ---------------------------------------------------------------------------
// Flash attention v8 (frozen structure; t-loop unroll 2 for static cur):
// 8 waves/block, grid 512 = qt(64) x head(8). LDS dbuf staging from dense
// k2/v2, one barrier/tile, constant-max in-register softmax, raw v_exp2,
// permlane pack. In-block 4-way combine.
// ---------------------------------------------------------------------------
__global__ __launch_bounds__(512, 4) void attn_k(const bf16* __restrict__ q2,
                                                 const bf16* __restrict__ k2,
                                                 const bf16* __restrict__ v2,
                                                 bf16* __restrict__ attnb) {
  const int bid = blockIdx.x;
  const int head = bid & 7;          // one head per XCD (L2 locality)
  const int qt = bid >> 3;
  const int w = threadIdx.x >> 6, l = threadIdx.x & 63;
  const int hi = l >> 5, l5 = l & 31;
  const int pair = w >> 1, wq = w & 1;

  __shared__ __align__(16) char smem[65536];
  char* kt_l = smem + pair * 16384;   // [2][4096] B
  char* vt_l = kt_l + 8192;           // [2][4096] B

  const int qrow0 = qt * 64 + wq * 32;
  const bf16* qb = q2 + (size_t)(qrow0 + l5) * 512 + head * 64;
  bf16x8 qf[4];
#pragma unroll
  for (int cc = 0; cc < 4; ++cc) qf[cc] = *(const bf16x8*)(qb + cc * 16 + hi * 8);

  const int kstart = pair * 1024;

  const int lr = l >> 3;
  const int lc3 = (l & 7) ^ lr;
  const char* kg = (const char*)k2 + (size_t)head * 524288 + (size_t)kstart * 128 +
                   (wq * 16 + lr) * 128 + lc3 * 16;
  const char* vg = (const char*)v2 + (size_t)head * 524288 + (size_t)(kstart >> 5) * 4096 +
                   (lc3 >> 2) * 2048 + (wq * 16 + lr) * 64 + (lc3 & 3) * 16;
  const int kdst = wq * 2048;

#define STAGE(B_)                                                            \
  do {                                                                       \
    gload_lds16(kg,        kt_l + (B_) * 4096 + kdst);                       \
    gload_lds16(kg + 1024, kt_l + (B_) * 4096 + kdst + 1024);                \
    gload_lds16(vg,        vt_l + (B_) * 4096 + kdst);                       \
    gload_lds16(vg + 512,  vt_l + (B_) * 4096 + kdst + 1024);                \
    kg += 4096; vg += 4096;                                                  \
  } while (0)

  STAGE(0);
  __syncthreads();

  f32x16 o0 = {}, o1 = {};
  float psum = 0.f;
  const int swl = l5 & 7;
  const char* kbase = kt_l + l5 * 128;
  const char* vbase = vt_l + l5 * 128;

#pragma unroll 2
  for (int t = 0; t < 32; ++t) {
    const int cur = t & 1;
    if (t < 31) STAGE(cur ^ 1);

    __builtin_amdgcn_s_setprio(1);
    f32x16 s = {};
#pragma unroll
    for (int cc = 0; cc < 4; ++cc) {
      bf16x8 kf = *(const bf16x8*)(kbase + cur * 4096 + ((cc * 2 + hi) ^ swl) * 16);
      s = MFMA32(kf, qf[cc], s);
    }
    __builtin_amdgcn_s_setprio(0);

#pragma unroll
    for (int c = 0; c < 2; ++c) {
      float p[8];
#pragma unroll
      for (int j = 0; j < 8; ++j) p[j] = fast_exp2(s[c * 8 + j]);
      psum += ((p[0] + p[1]) + (p[2] + p[3])) + ((p[4] + p[5]) + (p[6] + p[7]));
      unsigned X = pk2(p[0], p[1]), X2 = pk2(p[2], p[3]);
      unsigned Y = pk2(p[4], p[5]), Y2 = pk2(p[6], p[7]);
      asm volatile("v_permlane32_swap_b32 %0, %1" : "+v"(X), "+v"(Y));
      asm volatile("v_permlane32_swap_b32 %0, %1" : "+v"(X2), "+v"(Y2));
      union { unsigned wd[4]; bf16x8 v; } pa;
      pa.wd[0] = X; pa.wd[1] = X2; pa.wd[2] = Y; pa.wd[3] = Y2;
      bf16x8 vf0 = *(const bf16x8*)(vbase + cur * 4096 + ((c * 2 + hi) ^ swl) * 16);
      bf16x8 vf1 = *(const bf16x8*)(vbase + cur * 4096 + ((4 + c * 2 + hi) ^ swl) * 16);
      __builtin_amdgcn_s_setprio(1);
      o0 = MFMA32(vf0, pa.v, o0);
      o1 = MFMA32(vf1, pa.v, o1);
      __builtin_amdgcn_s_setprio(0);
    }
    __syncthreads();
  }
#undef STAGE

  // 4-way key-range combine via LDS (tiles dead). 6 slots x 64 x 33 f32.
  float* comb = (float*)smem;
  if (pair > 0) {
    float* cb = comb + (((pair - 1) * 2 + wq) * 64 + l) * 33;
#pragma unroll
    for (int r = 0; r < 16; ++r) { cb[r] = o0[r]; cb[16 + r] = o1[r]; }
    cb[32] = psum;
  }
  __syncthreads();
  if (pair == 0) {
#pragma unroll
    for (int p = 0; p < 3; ++p) {
      const float* cb = comb + ((p * 2 + wq) * 64 + l) * 33;
#pragma unroll
      for (int r = 0; r < 16; ++r) { o0[r] += cb[r]; o1[r] += cb[16 + r]; }
      psum += cb[32];
    }
    const float lsum = psum + __shfl_xor(psum, 32);
    const float inv = 1.f / lsum;
    bf16* ob = attnb + (size_t)(qrow0 + l5) * 512 + head * 64;
#pragma unroll
    for (int dt = 0; dt < 2; ++dt)
#pragma unroll
      for (int rg = 0; rg < 4; ++rg) {
        bf16x4 vv;
#pragma unroll
        for (int e = 0; e < 4; ++e) {
          const float ov = (dt == 0) ? o0[rg * 4 + e] : o1[rg * 4 + e];
          vv[e] = (bf16)(ov * inv);
        }
        *(bf16x4*)(ob + dt * 32 + rg * 8 + hi * 4) = vv;
      }
  }
}

// ---------------------------------------------------------------------------
extern "C" void kernel_launch(void* const* d_in, const int* in_sizes, int n_in,
                              void* d_out, int out_size, void* d_ws, size_t ws_size,
                              hipStream_t stream) {
  const float* x    = (const float*)d_in[0];
  const float* ln1s = (const float*)d_in[1];
  const float* ln1b = (const float*)d_in[2];
  const float* Wq   = (const float*)d_in[3];
  const float* bq   = (const float*)d_in[4];
  const float* Wk   = (const float*)d_in[5];
  const float* bk   = (const float*)d_in[6];
  const float* Wv   = (const float*)d_in[7];
  const float* bv   = (const float*)d_in[8];
  const float* Wo   = (const float*)d_in[9];
  const float* bo   = (const float*)d_in[10];
  const float* ln2s = (const float*)d_in[11];
  const float* ln2b = (const float*)d_in[12];
  const float* W1   = (const float*)d_in[13];
  const float* b1   = (const float*)d_in[14];
  const float* W2   = (const float*)d_in[15];
  const float* b2   = (const float*)d_in[16];
  float* out = (float*)d_out;

  char* ws = (char*)d_ws;
  bf16*  wqkvT = (bf16*)(ws + 0);          // [1536][512] 1.5M
  bf16*  woT   = (bf16*)(ws + 1572864);    // [512][512]  0.5M
  bf16*  w1T   = (bf16*)(ws + 2097152);    // [2048][512] 2M
  bf16*  w2T   = (bf16*)(ws + 4194304);    // [512][2048] 2M
  float* bqkv  = (float*)(ws + 6291456);   // -> 6297600
  float* x2    = (float*)(ws + 6297600);   // [4096][512] f32 8M -> 14686208
  bf16*  h     = (bf16*)(ws + 14686208);   // 4M -> 18880512 (h / attnb / h2)
  bf16*  q2    = (bf16*)(ws + 18880512);   // 4M -> 23074816
  bf16*  k2    = (bf16*)(ws + 23074816);   // 4M -> 27269120
  bf16*  v2    = (bf16*)(ws + 27269120);   // 4M -> 31463424
  bf16*  attnb = h;
  bf16*  h2    = h;
  bf16*  gbuf  = (bf16*)(ws + 18880512);   // ffn1 out 16M over dead q2/k2/v2

  prep_ln<<<1798, 256, 0, stream>>>(Wq, Wk, Wv, Wo, W1, W2, bq, bk, bv,
                                    wqkvT, woT, w1T, w2T, bqkv, x, ln1s, ln1b, h);
  gemm_w<3><<<dim3(32, 12), 256, 0, stream>>>(h, wqkvT, bqkv, q2, k2, v2,
                                              4096, 1536, 512);
  attn_k<<<512, 512, 0, stream>>>(q2, k2, v2, attnb);
  // wo projection: x2 = attnb @ Wo^T + bo + x
  gemm_n64<1><<<dim3(32, 8), 256, 0, stream>>>(attnb, woT, bo, x, x2, 4096, 512, 512);
  ln_k<<<1024, 256, 0, stream>>>(x2, ln2s, ln2b, h2);
  gemm_w<2><<<dim3(32, 16), 256, 0, stream>>>(h2, w1T, b1, gbuf, nullptr, nullptr,
                                              4096, 2048, 512);
  // ffn2: out = gbuf @ W2^T + b2 + x2
  gemm_n64<1><<<dim3(32, 8), 256, 0, stream>>>(gbuf, w2T, b2, x2, out, 4096, 512, 2048);
}